// Round 6
// baseline (923.555 us; speedup 1.0000x reference)
//
#include <hip/hip_runtime.h>

#define N_NODES 100000
#define N_EDGES 1200000
#define R_REL 3
#define RN (R_REL * N_NODES)   // 300000
#define RE (R_REL * N_EDGES)   // 3600000

// bucket sort params
#define B_BITS 9
#define W_BKT 512                       // nodes per bucket
#define NB_R 196                        // ceil(N_NODES / W_BKT)
#define K_BKT (R_REL * NB_R)            // 588 buckets
#define TILE_A 8192
#define NBLK_A ((RE + TILE_A - 1) / TILE_A)  // 440

__device__ __forceinline__ float bcast(float v, int l) {
  return __int_as_float(__builtin_amdgcn_readlane(__float_as_int(v), l));
}

__device__ __forceinline__ int rel_of(int e) {
  return (e >= 2 * N_EDGES) ? 2 : (e >= N_EDGES ? 1 : 0);
}

// ---------------- CSR build: two-level LDS-staged counting sort ----------------
// Pass 1: per-tile LDS histogram over 588 coarse buckets -> global totals
__global__ __launch_bounds__(256) void k_hist(const int* __restrict__ dst,
                                              int* __restrict__ tot) {
  __shared__ int sh[K_BKT];
  int tid = threadIdx.x;
  for (int i = tid; i < K_BKT; i += 256) sh[i] = 0;
  __syncthreads();
  int base = blockIdx.x * TILE_A;
  int end = min(base + TILE_A, RE);
  for (int e = base + tid; e < end; e += 256) {
    atomicAdd(&sh[rel_of(e) * NB_R + (dst[e] >> B_BITS)], 1);
  }
  __syncthreads();
  for (int i = tid; i < K_BKT; i += 256) {
    int c = sh[i];
    if (c) atomicAdd(&tot[i], c);
  }
}

// Pass 2: exclusive scan of 588 bucket totals -> bucket bases BB + global cursors
__global__ void k_scanK(const int* __restrict__ tot, int* __restrict__ BB,
                        int* __restrict__ cursor) {
  __shared__ int sd[256];
  int t = threadIdx.x;
  int v[3];
  int tots = 0;
#pragma unroll
  for (int q = 0; q < 3; q++) {
    int k = t * 3 + q;
    v[q] = (k < K_BKT) ? tot[k] : 0;
    tots += v[q];
  }
  sd[t] = tots;
  __syncthreads();
  for (int off = 1; off < 256; off <<= 1) {
    int x = (t >= off) ? sd[t - off] : 0;
    __syncthreads();
    sd[t] += x;
    __syncthreads();
  }
  int run = sd[t] - tots;
#pragma unroll
  for (int q = 0; q < 3; q++) {
    int k = t * 3 + q;
    if (k < K_BKT) {
      BB[k] = run;
      cursor[k] = run;
    }
    run += v[q];
  }
  if (t == 255) BB[K_BKT] = RE;
}

// Pass 3: scatter packed records (src<<9 | dst&511) into bucket-contiguous regions.
__global__ __launch_bounds__(256) void k_scatterA(const int* __restrict__ src,
                                                  const int* __restrict__ dst,
                                                  int* __restrict__ cursor,
                                                  unsigned int* __restrict__ rec) {
  __shared__ int sh[K_BKT];
  int tid = threadIdx.x;
  for (int i = tid; i < K_BKT; i += 256) sh[i] = 0;
  __syncthreads();
  int base = blockIdx.x * TILE_A;
  int end = min(base + TILE_A, RE);
  for (int e = base + tid; e < end; e += 256) {
    atomicAdd(&sh[rel_of(e) * NB_R + (dst[e] >> B_BITS)], 1);
  }
  __syncthreads();
  for (int i = tid; i < K_BKT; i += 256) {
    int c = sh[i];
    sh[i] = c ? atomicAdd(&cursor[i], c) : 0;  // own slot: no cross-thread hazard
  }
  __syncthreads();
  for (int e = base + tid; e < end; e += 256) {
    int d = dst[e];
    int k = rel_of(e) * NB_R + (d >> B_BITS);
    int p = atomicAdd(&sh[k], 1);
    rec[p] = ((unsigned)src[e] << B_BITS) | (unsigned)(d & (W_BKT - 1));
  }
}

// Pass 4: per-bucket counting sort (512 node slots in LDS) -> P (CSR offsets) + ssrc.
__global__ __launch_bounds__(256) void k_bsort(const unsigned int* __restrict__ rec,
                                               const int* __restrict__ BB,
                                               int* __restrict__ P,
                                               int* __restrict__ ssrc) {
  __shared__ int cnt[W_BKT];
  __shared__ int sd[256];
  int kb = blockIdx.x;
  int r = kb / NB_R;
  int nb0 = (kb % NB_R) * W_BKT;  // first node (within relation) of this bucket
  int beg = BB[kb], end = BB[kb + 1];
  int tid = threadIdx.x;
  cnt[tid] = 0;
  cnt[256 + tid] = 0;
  __syncthreads();
  for (int e = beg + tid; e < end; e += 256)
    atomicAdd(&cnt[rec[e] & (W_BKT - 1)], 1);
  __syncthreads();
  // block exclusive scan over 512 (2 elements per thread)
  int v0 = cnt[2 * tid], v1 = cnt[2 * tid + 1];
  int tot2 = v0 + v1;
  sd[tid] = tot2;
  __syncthreads();
  for (int off = 1; off < 256; off <<= 1) {
    int x = (tid >= off) ? sd[tid - off] : 0;
    __syncthreads();
    sd[tid] += x;
    __syncthreads();
  }
  int run = sd[tid] - tot2;
  int node0 = nb0 + 2 * tid;
  int pbase = r * N_NODES + node0;
  if (node0 < N_NODES) P[pbase] = beg + run;
  if (node0 + 1 < N_NODES) P[pbase + 1] = beg + run + v0;
  cnt[2 * tid] = beg + run;
  cnt[2 * tid + 1] = beg + run + v0;
  __syncthreads();
  for (int e = beg + tid; e < end; e += 256) {
    unsigned rc = rec[e];
    int p = atomicAdd(&cnt[rc & (W_BKT - 1)], 1);
    ssrc[p] = (int)(rc >> B_BITS);
  }
}

// ---------------- node transforms ----------------
// hp[r][n][64] = h@w_w[r]+w_b[r]
// pk[r][n][8]  = { a0, sdot, a1, sdot, a2, sdot, a3, sdot }  (interleaved so the
//   edge loop reads (a_head, sdot) as ONE float2)
//   a_h  = dot(hp_head, wa0) + dot(es_head, wa2) + atten_b[r]
//   sdot = dot(es[n], beta_r[0:64])   (gate es-part, distributed over seg-sum)
// adst[r][n][4] = per-head dst attention part
__global__ __launch_bounds__(256) void k_node(
    const float* __restrict__ h, const float* __restrict__ d_w,
    const float* __restrict__ d_b, const float* __restrict__ w_w,
    const float* __restrict__ w_b, const float* __restrict__ atten_w,
    const float* __restrict__ atten_b, const float* __restrict__ beta,
    float* __restrict__ hp, float* __restrict__ pk, float* __restrict__ adst) {
  __shared__ float sW[4 * 4096];  // 64 KB: d_w, w_w[0..2], layout [m][k*64+c]
  int tid = threadIdx.x;
  for (int idx = tid; idx < 4096; idx += 256) {
    sW[idx] = d_w[idx];
    sW[4096 + idx] = w_w[idx];
    sW[8192 + idx] = w_w[4096 + idx];
    sW[12288 + idx] = w_w[8192 + idx];
  }
  __syncthreads();
  int lane = tid & 63, wid = tid >> 6;
  int wave = blockIdx.x * 4 + wid, nw = gridDim.x * 4;
  int k16 = lane & 15, hgrp = lane >> 4;
  float dbv = d_b[lane];
  float wbv0 = w_b[lane], wbv1 = w_b[64 + lane], wbv2 = w_b[128 + lane];
  float wa0[3], wa1[3], wa2[3], ab[3], bb[3];
#pragma unroll
  for (int r = 0; r < 3; r++) {
    wa0[r] = atten_w[r * 48 + k16];
    wa1[r] = atten_w[r * 48 + 16 + k16];
    wa2[r] = atten_w[r * 48 + 32 + k16];
    ab[r] = atten_b[r];
    bb[r] = beta[r * 128 + lane];  // es-part of gate beta
  }
  for (int g = wave; g < N_NODES / 8; g += nw) {
    int n0 = g * 8;
    float hr[8];
#pragma unroll
    for (int i = 0; i < 8; i++) hr[i] = h[(n0 + i) * 64 + lane];
    float acc[8][4];
#pragma unroll
    for (int i = 0; i < 8; i++) {
      acc[i][0] = dbv; acc[i][1] = wbv0; acc[i][2] = wbv1; acc[i][3] = wbv2;
    }
#pragma unroll 4
    for (int k = 0; k < 64; k++) {
      float w0 = sW[k * 64 + lane];
      float w1 = sW[4096 + k * 64 + lane];
      float w2 = sW[8192 + k * 64 + lane];
      float w3 = sW[12288 + k * 64 + lane];
#pragma unroll
      for (int i = 0; i < 8; i++) {
        float a = bcast(hr[i], k);
        acc[i][0] += a * w0; acc[i][1] += a * w1;
        acc[i][2] += a * w2; acc[i][3] += a * w3;
      }
    }
#pragma unroll
    for (int i = 0; i < 8; i++) {
      int n = n0 + i;
      float esv = tanhf(2.f * acc[i][0]);
#pragma unroll
      for (int r = 0; r < 3; r++) {
        int idxrn = r * N_NODES + n;
        float hpv = acc[i][1 + r];
        hp[(size_t)idxrn * 64 + lane] = hpv;
        float cs = hpv * wa0[r] + esv * wa2[r];
        float cd = hpv * wa1[r];
#pragma unroll
        for (int m = 1; m < 16; m <<= 1) {
          cs += __shfl_xor(cs, m);
          cd += __shfl_xor(cd, m);
        }
        float sv = esv * bb[r];
#pragma unroll
        for (int m = 1; m < 64; m <<= 1) sv += __shfl_xor(sv, m);
        if (k16 == 0) {
          float2 rec2 = make_float2(cs + ab[r], sv);
          *reinterpret_cast<float2*>(&pk[(size_t)idxrn * 8 + hgrp * 2]) = rec2;
          adst[(size_t)idxrn * 4 + hgrp] = cd;
        }
      }
    }
  }
}

// ---------------- fused: per-dst softmax-aggregate + gate + final linear ----------------
// Lane layout: slot = lane>>4 (one of 4 concurrent edges), c16 = lane&15 owns
// channels [c16*4, c16*4+3] (float4 of the hp row), head = c16>>2.
// R4-style direct per-slot ssrc loads (linear addresses -> compiler hoists them
// out of the dependent chain); pk read as one float2 {a_head, sdot}.
// NO LDS: lin_w (48 KB total) is permanently L2-resident; reading it directly
// removes the 50 KB LDS block (occupancy 6 -> 8 waves/SIMD) and the 3.6M
// LDS bank conflicts of the stride-196 staging buffer.
#define EDGE_BODY(EE, OA, DS, SD)                                        \
  {                                                                      \
    int s_ = ssrc[EE];                                                   \
    float2 pv_ = *reinterpret_cast<const float2*>(&pkr[s_ * 8 + head2]); \
    float4 hv_ = *reinterpret_cast<const float4*>(&hpr[s_ * 64 + cq]);   \
    float a_ = pv_.x + adh;                                              \
    a_ = a_ >= 0.f ? a_ : 0.01f * a_;                                    \
    float ex_ = __expf(a_);                                              \
    OA.x += ex_ * hv_.x;                                                 \
    OA.y += ex_ * hv_.y;                                                 \
    OA.z += ex_ * hv_.z;                                                 \
    OA.w += ex_ * hv_.w;                                                 \
    DS += ex_;                                                           \
    SD += pv_.y;                                                         \
  }

__global__ __launch_bounds__(512, 8) void k_fused(
    const float* __restrict__ hp, const float* __restrict__ pk,
    const float* __restrict__ adst, const int* __restrict__ P,
    const int* __restrict__ ssrc, const float* __restrict__ beta,
    const float* __restrict__ lin_w, const float* __restrict__ lin_b,
    float* __restrict__ out) {
  int tid = threadIdx.x;
  int lane = tid & 63, wid = tid >> 6;
  int g = blockIdx.x * 8 + wid;  // 4 nodes per wave
  int slot = lane >> 4;          // edge slot 0..3
  int c16 = lane & 15;           // channel-quad index
  int cq = c16 * 4;              // first channel of this lane's quad
  int head = c16 >> 2;           // head of these 4 channels
  int head2 = head * 2;          // float2 offset into pk record
  float y0 = lin_b[lane];
  float y[4] = {y0, y0, y0, y0};
  for (int r = 0; r < 3; r++) {
    const float* __restrict__ hpr = hp + (size_t)r * N_NODES * 64;
    const float* __restrict__ pkr = pk + (size_t)r * N_NODES * 8;
    const float* __restrict__ lwr = lin_w + r * 64 * 64;  // rows r*64..r*64+63
    float4 b1v = *reinterpret_cast<const float4*>(&beta[r * 128 + 64 + cq]);
    float4 hr4[4];
#pragma unroll
    for (int i = 0; i < 4; i++) {
      int n = g * 4 + i;
      int idxrn = r * N_NODES + n;
      int beg = P[idxrn];
      int end = (idxrn + 1 < RN) ? P[idxrn + 1] : RE;
      float adh = adst[idxrn * 4 + head];
      float4 hpv = *reinterpret_cast<const float4*>(&hpr[n * 64 + cq]);
      float4 oaA = {0.f, 0.f, 0.f, 0.f}, oaB = {0.f, 0.f, 0.f, 0.f};
      float dsA = 0.f, dsB = 0.f, sdA = 0.f, sdB = 0.f;
      int e = beg + slot;
      for (; e + 4 < end; e += 8) {
        EDGE_BODY(e, oaA, dsA, sdA);
        EDGE_BODY(e + 4, oaB, dsB, sdB);
      }
      if (e < end) EDGE_BODY(e, oaA, dsA, sdA);
      float4 oa;
      oa.x = oaA.x + oaB.x;
      oa.y = oaA.y + oaB.y;
      oa.z = oaA.z + oaB.z;
      oa.w = oaA.w + oaB.w;
      float ds = dsA + dsB, sd = sdA + sdB;
      // combine the 4 edge slots (lane bits 4,5)
      oa.x += __shfl_xor(oa.x, 16); oa.x += __shfl_xor(oa.x, 32);
      oa.y += __shfl_xor(oa.y, 16); oa.y += __shfl_xor(oa.y, 32);
      oa.z += __shfl_xor(oa.z, 16); oa.z += __shfl_xor(oa.z, 32);
      oa.w += __shfl_xor(oa.w, 16); oa.w += __shfl_xor(oa.w, 32);
      ds += __shfl_xor(ds, 16); ds += __shfl_xor(ds, 32);
      sd += __shfl_xor(sd, 16); sd += __shfl_xor(sd, 32);
      float inv = 1.f / fmaxf(ds, 1e-20f);
      float4 ov;
      ov.x = oa.x * inv; ov.y = oa.y * inv; ov.z = oa.z * inv; ov.w = oa.w * inv;
      float em = sd / fmaxf((float)(end - beg), 1.f);  // wave-uniform gate es-part
      float gc = ov.x * b1v.x + ov.y * b1v.y + ov.z * b1v.z + ov.w * b1v.w;
      gc += __shfl_xor(gc, 1); gc += __shfl_xor(gc, 2);
      gc += __shfl_xor(gc, 4); gc += __shfl_xor(gc, 8);
      float gt = 1.f / (1.f + __expf(-(gc + em)));
      float4 hrv;
      hrv.x = gt * ov.x + (1.f - gt) * hpv.x;
      hrv.y = gt * ov.y + (1.f - gt) * hpv.y;
      hrv.z = gt * ov.z + (1.f - gt) * hpv.z;
      hrv.w = gt * ov.w + (1.f - gt) * hpv.w;
      hr4[i] = hrv;
    }
    // final linear from global lin_w (L2-resident): per j4, 4 coalesced scalar
    // loads (independent addresses -> compiler batches them)
#pragma unroll
    for (int j4 = 0; j4 < 64; j4 += 4) {
      float w0 = lwr[(j4 + 0) * 64 + lane];
      float w1 = lwr[(j4 + 1) * 64 + lane];
      float w2 = lwr[(j4 + 2) * 64 + lane];
      float w3 = lwr[(j4 + 3) * 64 + lane];
      const int sl = j4 >> 2;  // lane holding channels j4..j4+3 (words x..w)
#pragma unroll
      for (int i = 0; i < 4; i++) {
        y[i] += bcast(hr4[i].x, sl) * w0 + bcast(hr4[i].y, sl) * w1 +
                bcast(hr4[i].z, sl) * w2 + bcast(hr4[i].w, sl) * w3;
      }
    }
  }
#pragma unroll
  for (int i = 0; i < 4; i++) out[(g * 4 + i) * 64 + lane] = y[i];
}

extern "C" void kernel_launch(void* const* d_in, const int* in_sizes, int n_in,
                              void* d_out, int out_size, void* d_ws, size_t ws_size,
                              hipStream_t stream) {
  const float* h = (const float*)d_in[0];
  const int* src = (const int*)d_in[1];
  const int* dst = (const int*)d_in[2];
  const float* d_w = (const float*)d_in[3];
  const float* d_b = (const float*)d_in[4];
  const float* w_w = (const float*)d_in[5];
  const float* w_b = (const float*)d_in[6];
  const float* atten_w = (const float*)d_in[7];
  const float* atten_b = (const float*)d_in[8];
  const float* beta = (const float*)d_in[9];
  const float* lin_w = (const float*)d_in[10];
  const float* lin_b = (const float*)d_in[11];
  float* out = (float*)d_out;

  float* ws = (float*)d_ws;
  float* hp = ws;                                      // R*N*64
  float* pk = hp + (size_t)R_REL * N_NODES * 64;       // R*N*8
  float* adst = pk + (size_t)R_REL * N_NODES * 8;      // R*N*4
  int* P = (int*)(adst + (size_t)R_REL * N_NODES * 4); // RN
  int* ssrc = P + RN;                                  // RE
  unsigned int* rec = (unsigned int*)(ssrc + RE);      // RE
  int* tot = (int*)(rec + RE);                         // K_BKT
  int* BB = tot + K_BKT;                               // K_BKT+1
  int* cursor = BB + K_BKT + 1;                        // K_BKT

  hipMemsetAsync(tot, 0, K_BKT * sizeof(int), stream);
  k_hist<<<NBLK_A, 256, 0, stream>>>(dst, tot);
  k_scanK<<<1, 256, 0, stream>>>(tot, BB, cursor);
  k_scatterA<<<NBLK_A, 256, 0, stream>>>(src, dst, cursor, rec);
  k_bsort<<<K_BKT, 256, 0, stream>>>(rec, BB, P, ssrc);
  k_node<<<1024, 256, 0, stream>>>(h, d_w, d_b, w_w, w_b, atten_w, atten_b, beta,
                                   hp, pk, adst);
  k_fused<<<N_NODES / 32, 512, 0, stream>>>(hp, pk, adst, P, ssrc, beta, lin_w,
                                            lin_b, out);
}

// Round 7
// 838.527 us; speedup vs baseline: 1.1014x; 1.1014x over previous
//
#include <hip/hip_runtime.h>

#define N_NODES 100000
#define N_EDGES 1200000
#define R_REL 3
#define RN (R_REL * N_NODES)   // 300000
#define RE (R_REL * N_EDGES)   // 3600000

// bucket sort params
#define B_BITS 9
#define W_BKT 512                       // nodes per bucket
#define NB_R 196                        // ceil(N_NODES / W_BKT)
#define K_BKT (R_REL * NB_R)            // 588 buckets
#define TILE_A 8192
#define NBLK_A ((RE + TILE_A - 1) / TILE_A)  // 440

__device__ __forceinline__ float bcast(float v, int l) {
  return __int_as_float(__builtin_amdgcn_readlane(__float_as_int(v), l));
}

__device__ __forceinline__ int rel_of(int e) {
  return (e >= 2 * N_EDGES) ? 2 : (e >= N_EDGES ? 1 : 0);
}

// ---------------- CSR build: two-level LDS-staged counting sort ----------------
__global__ __launch_bounds__(256) void k_hist(const int* __restrict__ dst,
                                              int* __restrict__ tot) {
  __shared__ int sh[K_BKT];
  int tid = threadIdx.x;
  for (int i = tid; i < K_BKT; i += 256) sh[i] = 0;
  __syncthreads();
  int base = blockIdx.x * TILE_A;
  int end = min(base + TILE_A, RE);
  for (int e = base + tid; e < end; e += 256) {
    atomicAdd(&sh[rel_of(e) * NB_R + (dst[e] >> B_BITS)], 1);
  }
  __syncthreads();
  for (int i = tid; i < K_BKT; i += 256) {
    int c = sh[i];
    if (c) atomicAdd(&tot[i], c);
  }
}

__global__ void k_scanK(const int* __restrict__ tot, int* __restrict__ BB,
                        int* __restrict__ cursor) {
  __shared__ int sd[256];
  int t = threadIdx.x;
  int v[3];
  int tots = 0;
#pragma unroll
  for (int q = 0; q < 3; q++) {
    int k = t * 3 + q;
    v[q] = (k < K_BKT) ? tot[k] : 0;
    tots += v[q];
  }
  sd[t] = tots;
  __syncthreads();
  for (int off = 1; off < 256; off <<= 1) {
    int x = (t >= off) ? sd[t - off] : 0;
    __syncthreads();
    sd[t] += x;
    __syncthreads();
  }
  int run = sd[t] - tots;
#pragma unroll
  for (int q = 0; q < 3; q++) {
    int k = t * 3 + q;
    if (k < K_BKT) {
      BB[k] = run;
      cursor[k] = run;
    }
    run += v[q];
  }
  if (t == 255) BB[K_BKT] = RE;
}

__global__ __launch_bounds__(256) void k_scatterA(const int* __restrict__ src,
                                                  const int* __restrict__ dst,
                                                  int* __restrict__ cursor,
                                                  unsigned int* __restrict__ rec) {
  __shared__ int sh[K_BKT];
  int tid = threadIdx.x;
  for (int i = tid; i < K_BKT; i += 256) sh[i] = 0;
  __syncthreads();
  int base = blockIdx.x * TILE_A;
  int end = min(base + TILE_A, RE);
  for (int e = base + tid; e < end; e += 256) {
    atomicAdd(&sh[rel_of(e) * NB_R + (dst[e] >> B_BITS)], 1);
  }
  __syncthreads();
  for (int i = tid; i < K_BKT; i += 256) {
    int c = sh[i];
    sh[i] = c ? atomicAdd(&cursor[i], c) : 0;  // own slot: no cross-thread hazard
  }
  __syncthreads();
  for (int e = base + tid; e < end; e += 256) {
    int d = dst[e];
    int k = rel_of(e) * NB_R + (d >> B_BITS);
    int p = atomicAdd(&sh[k], 1);
    rec[p] = ((unsigned)src[e] << B_BITS) | (unsigned)(d & (W_BKT - 1));
  }
}

__global__ __launch_bounds__(256) void k_bsort(const unsigned int* __restrict__ rec,
                                               const int* __restrict__ BB,
                                               int* __restrict__ P,
                                               int* __restrict__ ssrc) {
  __shared__ int cnt[W_BKT];
  __shared__ int sd[256];
  int kb = blockIdx.x;
  int r = kb / NB_R;
  int nb0 = (kb % NB_R) * W_BKT;  // first node (within relation) of this bucket
  int beg = BB[kb], end = BB[kb + 1];
  int tid = threadIdx.x;
  cnt[tid] = 0;
  cnt[256 + tid] = 0;
  __syncthreads();
  for (int e = beg + tid; e < end; e += 256)
    atomicAdd(&cnt[rec[e] & (W_BKT - 1)], 1);
  __syncthreads();
  // block exclusive scan over 512 (2 elements per thread)
  int v0 = cnt[2 * tid], v1 = cnt[2 * tid + 1];
  int tot2 = v0 + v1;
  sd[tid] = tot2;
  __syncthreads();
  for (int off = 1; off < 256; off <<= 1) {
    int x = (tid >= off) ? sd[tid - off] : 0;
    __syncthreads();
    sd[tid] += x;
    __syncthreads();
  }
  int run = sd[tid] - tot2;
  int node0 = nb0 + 2 * tid;
  int pbase = r * N_NODES + node0;
  if (node0 < N_NODES) P[pbase] = beg + run;
  if (node0 + 1 < N_NODES) P[pbase + 1] = beg + run + v0;
  cnt[2 * tid] = beg + run;
  cnt[2 * tid + 1] = beg + run + v0;
  __syncthreads();
  for (int e = beg + tid; e < end; e += 256) {
    unsigned rc = rec[e];
    int p = atomicAdd(&cnt[rc & (W_BKT - 1)], 1);
    ssrc[p] = (int)(rc >> B_BITS);
  }
}

// ---------------- node transforms ----------------
// hp[r][n][64] = h@w_w[r]+w_b[r]
// pk[r][n][8]  = { a0, sdot, a1, sdot, a2, sdot, a3, sdot }
// adst[r][n][4] = per-head dst attention part
__global__ __launch_bounds__(256) void k_node(
    const float* __restrict__ h, const float* __restrict__ d_w,
    const float* __restrict__ d_b, const float* __restrict__ w_w,
    const float* __restrict__ w_b, const float* __restrict__ atten_w,
    const float* __restrict__ atten_b, const float* __restrict__ beta,
    float* __restrict__ hp, float* __restrict__ pk, float* __restrict__ adst) {
  __shared__ float sW[4 * 4096];  // 64 KB: d_w, w_w[0..2], layout [m][k*64+c]
  int tid = threadIdx.x;
  for (int idx = tid; idx < 4096; idx += 256) {
    sW[idx] = d_w[idx];
    sW[4096 + idx] = w_w[idx];
    sW[8192 + idx] = w_w[4096 + idx];
    sW[12288 + idx] = w_w[8192 + idx];
  }
  __syncthreads();
  int lane = tid & 63, wid = tid >> 6;
  int wave = blockIdx.x * 4 + wid, nw = gridDim.x * 4;
  int k16 = lane & 15, hgrp = lane >> 4;
  float dbv = d_b[lane];
  float wbv0 = w_b[lane], wbv1 = w_b[64 + lane], wbv2 = w_b[128 + lane];
  float wa0[3], wa1[3], wa2[3], ab[3], bb[3];
#pragma unroll
  for (int r = 0; r < 3; r++) {
    wa0[r] = atten_w[r * 48 + k16];
    wa1[r] = atten_w[r * 48 + 16 + k16];
    wa2[r] = atten_w[r * 48 + 32 + k16];
    ab[r] = atten_b[r];
    bb[r] = beta[r * 128 + lane];  // es-part of gate beta
  }
  for (int g = wave; g < N_NODES / 8; g += nw) {
    int n0 = g * 8;
    float hr[8];
#pragma unroll
    for (int i = 0; i < 8; i++) hr[i] = h[(n0 + i) * 64 + lane];
    float acc[8][4];
#pragma unroll
    for (int i = 0; i < 8; i++) {
      acc[i][0] = dbv; acc[i][1] = wbv0; acc[i][2] = wbv1; acc[i][3] = wbv2;
    }
#pragma unroll 4
    for (int k = 0; k < 64; k++) {
      float w0 = sW[k * 64 + lane];
      float w1 = sW[4096 + k * 64 + lane];
      float w2 = sW[8192 + k * 64 + lane];
      float w3 = sW[12288 + k * 64 + lane];
#pragma unroll
      for (int i = 0; i < 8; i++) {
        float a = bcast(hr[i], k);
        acc[i][0] += a * w0; acc[i][1] += a * w1;
        acc[i][2] += a * w2; acc[i][3] += a * w3;
      }
    }
#pragma unroll
    for (int i = 0; i < 8; i++) {
      int n = n0 + i;
      float esv = tanhf(2.f * acc[i][0]);
#pragma unroll
      for (int r = 0; r < 3; r++) {
        int idxrn = r * N_NODES + n;
        float hpv = acc[i][1 + r];
        hp[(size_t)idxrn * 64 + lane] = hpv;
        float cs = hpv * wa0[r] + esv * wa2[r];
        float cd = hpv * wa1[r];
#pragma unroll
        for (int m = 1; m < 16; m <<= 1) {
          cs += __shfl_xor(cs, m);
          cd += __shfl_xor(cd, m);
        }
        float sv = esv * bb[r];
#pragma unroll
        for (int m = 1; m < 64; m <<= 1) sv += __shfl_xor(sv, m);
        if (k16 == 0) {
          float2 rec2 = make_float2(cs + ab[r], sv);
          *reinterpret_cast<float2*>(&pk[(size_t)idxrn * 8 + hgrp * 2]) = rec2;
          adst[(size_t)idxrn * 4 + hgrp] = cd;
        }
      }
    }
  }
}

// ---------------- fused: per-dst softmax-aggregate + gate + final linear ----------------
// 1024-thread blocks (16 waves) share ONE 50 KB sLW copy -> 2 blocks/CU = 100 KB
// LDS = 32 waves/CU = 8 waves/SIMD (vs 6 with 512-thread blocks).
// Edge loop: R4-style direct ssrc loads (linear addrs, compiler prefetches);
// pk read as one float2 {a_head, sdot}. Epilogue from LDS (stride 196: lane
// bank-group offset = 4, the b128 hardware minimum).
#define EDGE_BODY(EE, OA, DS, SD)                                        \
  {                                                                      \
    int s_ = ssrc[EE];                                                   \
    float2 pv_ = *reinterpret_cast<const float2*>(&pkr[s_ * 8 + head2]); \
    float4 hv_ = *reinterpret_cast<const float4*>(&hpr[s_ * 64 + cq]);   \
    float a_ = pv_.x + adh;                                              \
    a_ = a_ >= 0.f ? a_ : 0.01f * a_;                                    \
    float ex_ = __expf(a_);                                              \
    OA.x += ex_ * hv_.x;                                                 \
    OA.y += ex_ * hv_.y;                                                 \
    OA.z += ex_ * hv_.z;                                                 \
    OA.w += ex_ * hv_.w;                                                 \
    DS += ex_;                                                           \
    SD += pv_.y;                                                         \
  }

__global__ __launch_bounds__(1024, 8) void k_fused(
    const float* __restrict__ hp, const float* __restrict__ pk,
    const float* __restrict__ adst, const int* __restrict__ P,
    const int* __restrict__ ssrc, const float* __restrict__ beta,
    const float* __restrict__ lin_w, const float* __restrict__ lin_b,
    float* __restrict__ out) {
  __shared__ __align__(16) float sLW[64 * 196];  // transposed lin_w: [c][j], stride 196
  int tid = threadIdx.x;
  for (int idx = tid; idx < 192 * 64; idx += 1024) {
    int j = idx >> 6, c = idx & 63;
    sLW[c * 196 + j] = lin_w[idx];
  }
  __syncthreads();
  int lane = tid & 63, wid = tid >> 6;
  int g = blockIdx.x * 16 + wid;  // 4 nodes per wave
  int slot = lane >> 4;           // edge slot 0..3
  int c16 = lane & 15;            // channel-quad index
  int cq = c16 * 4;               // first channel of this lane's quad
  int head = c16 >> 2;            // head of these 4 channels
  int head2 = head * 2;           // float2 offset into pk record
  float y0 = lin_b[lane];
  float y[4] = {y0, y0, y0, y0};
  for (int r = 0; r < 3; r++) {
    const float* __restrict__ hpr = hp + (size_t)r * N_NODES * 64;
    const float* __restrict__ pkr = pk + (size_t)r * N_NODES * 8;
    float4 b1v = *reinterpret_cast<const float4*>(&beta[r * 128 + 64 + cq]);
    float4 hr4[4];
#pragma unroll
    for (int i = 0; i < 4; i++) {
      int n = g * 4 + i;
      n = n < N_NODES ? n : N_NODES - 1;  // tail clamp: duplicate work, store-guarded
      int idxrn = r * N_NODES + n;
      int beg = P[idxrn];
      int end = (idxrn + 1 < RN) ? P[idxrn + 1] : RE;
      float adh = adst[idxrn * 4 + head];
      float4 hpv = *reinterpret_cast<const float4*>(&hpr[n * 64 + cq]);
      float4 oaA = {0.f, 0.f, 0.f, 0.f}, oaB = {0.f, 0.f, 0.f, 0.f};
      float dsA = 0.f, dsB = 0.f, sdA = 0.f, sdB = 0.f;
      int e = beg + slot;
      for (; e + 4 < end; e += 8) {
        EDGE_BODY(e, oaA, dsA, sdA);
        EDGE_BODY(e + 4, oaB, dsB, sdB);
      }
      if (e < end) EDGE_BODY(e, oaA, dsA, sdA);
      float4 oa;
      oa.x = oaA.x + oaB.x;
      oa.y = oaA.y + oaB.y;
      oa.z = oaA.z + oaB.z;
      oa.w = oaA.w + oaB.w;
      float ds = dsA + dsB, sd = sdA + sdB;
      // combine the 4 edge slots (lane bits 4,5)
      oa.x += __shfl_xor(oa.x, 16); oa.x += __shfl_xor(oa.x, 32);
      oa.y += __shfl_xor(oa.y, 16); oa.y += __shfl_xor(oa.y, 32);
      oa.z += __shfl_xor(oa.z, 16); oa.z += __shfl_xor(oa.z, 32);
      oa.w += __shfl_xor(oa.w, 16); oa.w += __shfl_xor(oa.w, 32);
      ds += __shfl_xor(ds, 16); ds += __shfl_xor(ds, 32);
      sd += __shfl_xor(sd, 16); sd += __shfl_xor(sd, 32);
      float inv = 1.f / fmaxf(ds, 1e-20f);
      float4 ov;
      ov.x = oa.x * inv; ov.y = oa.y * inv; ov.z = oa.z * inv; ov.w = oa.w * inv;
      float em = sd / fmaxf((float)(end - beg), 1.f);  // wave-uniform gate es-part
      float gc = ov.x * b1v.x + ov.y * b1v.y + ov.z * b1v.z + ov.w * b1v.w;
      gc += __shfl_xor(gc, 1); gc += __shfl_xor(gc, 2);
      gc += __shfl_xor(gc, 4); gc += __shfl_xor(gc, 8);
      float gt = 1.f / (1.f + __expf(-(gc + em)));
      float4 hrv;
      hrv.x = gt * ov.x + (1.f - gt) * hpv.x;
      hrv.y = gt * ov.y + (1.f - gt) * hpv.y;
      hrv.z = gt * ov.z + (1.f - gt) * hpv.z;
      hrv.w = gt * ov.w + (1.f - gt) * hpv.w;
      hr4[i] = hrv;
    }
    const float* wrow = &sLW[lane * 196 + r * 64];
#pragma unroll
    for (int j4 = 0; j4 < 64; j4 += 4) {
      float4 wv = *reinterpret_cast<const float4*>(wrow + j4);
      const int sl = j4 >> 2;  // lane holding channels j4..j4+3 (words x..w)
#pragma unroll
      for (int i = 0; i < 4; i++) {
        y[i] += bcast(hr4[i].x, sl) * wv.x + bcast(hr4[i].y, sl) * wv.y +
                bcast(hr4[i].z, sl) * wv.z + bcast(hr4[i].w, sl) * wv.w;
      }
    }
  }
#pragma unroll
  for (int i = 0; i < 4; i++) {
    int n = g * 4 + i;
    if (n < N_NODES) out[n * 64 + lane] = y[i];
  }
}

extern "C" void kernel_launch(void* const* d_in, const int* in_sizes, int n_in,
                              void* d_out, int out_size, void* d_ws, size_t ws_size,
                              hipStream_t stream) {
  const float* h = (const float*)d_in[0];
  const int* src = (const int*)d_in[1];
  const int* dst = (const int*)d_in[2];
  const float* d_w = (const float*)d_in[3];
  const float* d_b = (const float*)d_in[4];
  const float* w_w = (const float*)d_in[5];
  const float* w_b = (const float*)d_in[6];
  const float* atten_w = (const float*)d_in[7];
  const float* atten_b = (const float*)d_in[8];
  const float* beta = (const float*)d_in[9];
  const float* lin_w = (const float*)d_in[10];
  const float* lin_b = (const float*)d_in[11];
  float* out = (float*)d_out;

  float* ws = (float*)d_ws;
  float* hp = ws;                                      // R*N*64
  float* pk = hp + (size_t)R_REL * N_NODES * 64;       // R*N*8
  float* adst = pk + (size_t)R_REL * N_NODES * 8;      // R*N*4
  int* P = (int*)(adst + (size_t)R_REL * N_NODES * 4); // RN
  int* ssrc = P + RN;                                  // RE
  unsigned int* rec = (unsigned int*)(ssrc + RE);      // RE
  int* tot = (int*)(rec + RE);                         // K_BKT
  int* BB = tot + K_BKT;                               // K_BKT+1
  int* cursor = BB + K_BKT + 1;                        // K_BKT

  hipMemsetAsync(tot, 0, K_BKT * sizeof(int), stream);
  k_hist<<<NBLK_A, 256, 0, stream>>>(dst, tot);
  k_scanK<<<1, 256, 0, stream>>>(tot, BB, cursor);
  k_scatterA<<<NBLK_A, 256, 0, stream>>>(src, dst, cursor, rec);
  k_bsort<<<K_BKT, 256, 0, stream>>>(rec, BB, P, ssrc);
  k_node<<<1024, 256, 0, stream>>>(h, d_w, d_b, w_w, w_b, atten_w, atten_b, beta,
                                   hp, pk, adst);
  int nfb = (N_NODES + 63) / 64;  // 64 nodes per 1024-thread block
  k_fused<<<nfb, 1024, 0, stream>>>(hp, pk, adst, P, ssrc, beta, lin_w,
                                    lin_b, out);
}

// Round 8
// 616.013 us; speedup vs baseline: 1.4992x; 1.3612x over previous
//
#include <hip/hip_runtime.h>

#define N_NODES 100000
#define N_EDGES 1200000
#define R_REL 3
#define RN (R_REL * N_NODES)   // 300000
#define RE (R_REL * N_EDGES)   // 3600000

// bucket sort params
#define B_BITS 9
#define W_BKT 512                       // nodes per bucket
#define NB_R 196                        // ceil(N_NODES / W_BKT)
#define K_BKT (R_REL * NB_R)            // 588 buckets
#define TILE_A 8192
#define NBLK_A ((RE + TILE_A - 1) / TILE_A)  // 440

__device__ __forceinline__ float bcast(float v, int l) {
  return __int_as_float(__builtin_amdgcn_readlane(__float_as_int(v), l));
}

__device__ __forceinline__ int rel_of(int e) {
  return (e >= 2 * N_EDGES) ? 2 : (e >= N_EDGES ? 1 : 0);
}

// ---------------- CSR build: two-level LDS-staged counting sort ----------------
__global__ __launch_bounds__(256) void k_hist(const int* __restrict__ dst,
                                              int* __restrict__ tot) {
  __shared__ int sh[K_BKT];
  int tid = threadIdx.x;
  for (int i = tid; i < K_BKT; i += 256) sh[i] = 0;
  __syncthreads();
  int base = blockIdx.x * TILE_A;
  int end = min(base + TILE_A, RE);
  for (int e = base + tid; e < end; e += 256) {
    atomicAdd(&sh[rel_of(e) * NB_R + (dst[e] >> B_BITS)], 1);
  }
  __syncthreads();
  for (int i = tid; i < K_BKT; i += 256) {
    int c = sh[i];
    if (c) atomicAdd(&tot[i], c);
  }
}

__global__ void k_scanK(const int* __restrict__ tot, int* __restrict__ BB,
                        int* __restrict__ cursor) {
  __shared__ int sd[256];
  int t = threadIdx.x;
  int v[3];
  int tots = 0;
#pragma unroll
  for (int q = 0; q < 3; q++) {
    int k = t * 3 + q;
    v[q] = (k < K_BKT) ? tot[k] : 0;
    tots += v[q];
  }
  sd[t] = tots;
  __syncthreads();
  for (int off = 1; off < 256; off <<= 1) {
    int x = (t >= off) ? sd[t - off] : 0;
    __syncthreads();
    sd[t] += x;
    __syncthreads();
  }
  int run = sd[t] - tots;
#pragma unroll
  for (int q = 0; q < 3; q++) {
    int k = t * 3 + q;
    if (k < K_BKT) {
      BB[k] = run;
      cursor[k] = run;
    }
    run += v[q];
  }
  if (t == 255) BB[K_BKT] = RE;
}

__global__ __launch_bounds__(256) void k_scatterA(const int* __restrict__ src,
                                                  const int* __restrict__ dst,
                                                  int* __restrict__ cursor,
                                                  unsigned int* __restrict__ rec) {
  __shared__ int sh[K_BKT];
  int tid = threadIdx.x;
  for (int i = tid; i < K_BKT; i += 256) sh[i] = 0;
  __syncthreads();
  int base = blockIdx.x * TILE_A;
  int end = min(base + TILE_A, RE);
  for (int e = base + tid; e < end; e += 256) {
    atomicAdd(&sh[rel_of(e) * NB_R + (dst[e] >> B_BITS)], 1);
  }
  __syncthreads();
  for (int i = tid; i < K_BKT; i += 256) {
    int c = sh[i];
    sh[i] = c ? atomicAdd(&cursor[i], c) : 0;  // own slot: no cross-thread hazard
  }
  __syncthreads();
  for (int e = base + tid; e < end; e += 256) {
    int d = dst[e];
    int k = rel_of(e) * NB_R + (d >> B_BITS);
    int p = atomicAdd(&sh[k], 1);
    rec[p] = ((unsigned)src[e] << B_BITS) | (unsigned)(d & (W_BKT - 1));
  }
}

__global__ __launch_bounds__(256) void k_bsort(const unsigned int* __restrict__ rec,
                                               const int* __restrict__ BB,
                                               int* __restrict__ P,
                                               int* __restrict__ ssrc) {
  __shared__ int cnt[W_BKT];
  __shared__ int sd[256];
  int kb = blockIdx.x;
  int r = kb / NB_R;
  int nb0 = (kb % NB_R) * W_BKT;  // first node (within relation) of this bucket
  int beg = BB[kb], end = BB[kb + 1];
  int tid = threadIdx.x;
  cnt[tid] = 0;
  cnt[256 + tid] = 0;
  __syncthreads();
  for (int e = beg + tid; e < end; e += 256)
    atomicAdd(&cnt[rec[e] & (W_BKT - 1)], 1);
  __syncthreads();
  // block exclusive scan over 512 (2 elements per thread)
  int v0 = cnt[2 * tid], v1 = cnt[2 * tid + 1];
  int tot2 = v0 + v1;
  sd[tid] = tot2;
  __syncthreads();
  for (int off = 1; off < 256; off <<= 1) {
    int x = (tid >= off) ? sd[tid - off] : 0;
    __syncthreads();
    sd[tid] += x;
    __syncthreads();
  }
  int run = sd[tid] - tot2;
  int node0 = nb0 + 2 * tid;
  int pbase = r * N_NODES + node0;
  if (node0 < N_NODES) P[pbase] = beg + run;
  if (node0 + 1 < N_NODES) P[pbase + 1] = beg + run + v0;
  cnt[2 * tid] = beg + run;
  cnt[2 * tid + 1] = beg + run + v0;
  __syncthreads();
  for (int e = beg + tid; e < end; e += 256) {
    unsigned rc = rec[e];
    int p = atomicAdd(&cnt[rc & (W_BKT - 1)], 1);
    ssrc[p] = (int)(rc >> B_BITS);
  }
}

// ---------------- node transforms ----------------
// hp[r][n][64] = h@w_w[r]+w_b[r]
// pk[r][n][8]  = { a0, sdot, a1, sdot, a2, sdot, a3, sdot }
// adst[r][n][4] = per-head dst attention part
__global__ __launch_bounds__(256) void k_node(
    const float* __restrict__ h, const float* __restrict__ d_w,
    const float* __restrict__ d_b, const float* __restrict__ w_w,
    const float* __restrict__ w_b, const float* __restrict__ atten_w,
    const float* __restrict__ atten_b, const float* __restrict__ beta,
    float* __restrict__ hp, float* __restrict__ pk, float* __restrict__ adst) {
  __shared__ float sW[4 * 4096];  // 64 KB: d_w, w_w[0..2], layout [m][k*64+c]
  int tid = threadIdx.x;
  for (int idx = tid; idx < 4096; idx += 256) {
    sW[idx] = d_w[idx];
    sW[4096 + idx] = w_w[idx];
    sW[8192 + idx] = w_w[4096 + idx];
    sW[12288 + idx] = w_w[8192 + idx];
  }
  __syncthreads();
  int lane = tid & 63, wid = tid >> 6;
  int wave = blockIdx.x * 4 + wid, nw = gridDim.x * 4;
  int k16 = lane & 15, hgrp = lane >> 4;
  float dbv = d_b[lane];
  float wbv0 = w_b[lane], wbv1 = w_b[64 + lane], wbv2 = w_b[128 + lane];
  float wa0[3], wa1[3], wa2[3], ab[3], bb[3];
#pragma unroll
  for (int r = 0; r < 3; r++) {
    wa0[r] = atten_w[r * 48 + k16];
    wa1[r] = atten_w[r * 48 + 16 + k16];
    wa2[r] = atten_w[r * 48 + 32 + k16];
    ab[r] = atten_b[r];
    bb[r] = beta[r * 128 + lane];  // es-part of gate beta
  }
  for (int g = wave; g < N_NODES / 8; g += nw) {
    int n0 = g * 8;
    float hr[8];
#pragma unroll
    for (int i = 0; i < 8; i++) hr[i] = h[(n0 + i) * 64 + lane];
    float acc[8][4];
#pragma unroll
    for (int i = 0; i < 8; i++) {
      acc[i][0] = dbv; acc[i][1] = wbv0; acc[i][2] = wbv1; acc[i][3] = wbv2;
    }
#pragma unroll 4
    for (int k = 0; k < 64; k++) {
      float w0 = sW[k * 64 + lane];
      float w1 = sW[4096 + k * 64 + lane];
      float w2 = sW[8192 + k * 64 + lane];
      float w3 = sW[12288 + k * 64 + lane];
#pragma unroll
      for (int i = 0; i < 8; i++) {
        float a = bcast(hr[i], k);
        acc[i][0] += a * w0; acc[i][1] += a * w1;
        acc[i][2] += a * w2; acc[i][3] += a * w3;
      }
    }
#pragma unroll
    for (int i = 0; i < 8; i++) {
      int n = n0 + i;
      float esv = tanhf(2.f * acc[i][0]);
#pragma unroll
      for (int r = 0; r < 3; r++) {
        int idxrn = r * N_NODES + n;
        float hpv = acc[i][1 + r];
        hp[(size_t)idxrn * 64 + lane] = hpv;
        float cs = hpv * wa0[r] + esv * wa2[r];
        float cd = hpv * wa1[r];
#pragma unroll
        for (int m = 1; m < 16; m <<= 1) {
          cs += __shfl_xor(cs, m);
          cd += __shfl_xor(cd, m);
        }
        float sv = esv * bb[r];
#pragma unroll
        for (int m = 1; m < 64; m <<= 1) sv += __shfl_xor(sv, m);
        if (k16 == 0) {
          float2 rec2 = make_float2(cs + ab[r], sv);
          *reinterpret_cast<float2*>(&pk[(size_t)idxrn * 8 + hgrp * 2]) = rec2;
          adst[(size_t)idxrn * 4 + hgrp] = cd;
        }
      }
    }
  }
}

// ---------------- fused: per-dst softmax-aggregate + gate + final linear ----------------
// 1024-thread blocks (16 waves) share ONE 50 KB sLW copy -> 2 blocks/CU = 100 KB
// LDS = 32 waves/CU = 8 waves/SIMD.
// __launch_bounds__(1024, 2): second arg is MIN BLOCKS PER CU on this toolchain
// (R6/R7 evidence: arg=8 -> 16 waves/SIMD target -> 32-VGPR cap -> spills).
// 2 blocks/CU -> 8 waves/SIMD -> 64-VGPR cap; body fits in ~60 (R5).
#define EDGE_BODY(EE, OA, DS, SD)                                        \
  {                                                                      \
    int s_ = ssrc[EE];                                                   \
    float2 pv_ = *reinterpret_cast<const float2*>(&pkr[s_ * 8 + head2]); \
    float4 hv_ = *reinterpret_cast<const float4*>(&hpr[s_ * 64 + cq]);   \
    float a_ = pv_.x + adh;                                              \
    a_ = a_ >= 0.f ? a_ : 0.01f * a_;                                    \
    float ex_ = __expf(a_);                                              \
    OA.x += ex_ * hv_.x;                                                 \
    OA.y += ex_ * hv_.y;                                                 \
    OA.z += ex_ * hv_.z;                                                 \
    OA.w += ex_ * hv_.w;                                                 \
    DS += ex_;                                                           \
    SD += pv_.y;                                                         \
  }

__global__ __launch_bounds__(1024, 2) void k_fused(
    const float* __restrict__ hp, const float* __restrict__ pk,
    const float* __restrict__ adst, const int* __restrict__ P,
    const int* __restrict__ ssrc, const float* __restrict__ beta,
    const float* __restrict__ lin_w, const float* __restrict__ lin_b,
    float* __restrict__ out) {
  __shared__ __align__(16) float sLW[64 * 196];  // transposed lin_w: [c][j], stride 196
  int tid = threadIdx.x;
  for (int idx = tid; idx < 192 * 64; idx += 1024) {
    int j = idx >> 6, c = idx & 63;
    sLW[c * 196 + j] = lin_w[idx];
  }
  __syncthreads();
  int lane = tid & 63, wid = tid >> 6;
  int g = blockIdx.x * 16 + wid;  // 4 nodes per wave
  int slot = lane >> 4;           // edge slot 0..3
  int c16 = lane & 15;            // channel-quad index
  int cq = c16 * 4;               // first channel of this lane's quad
  int head = c16 >> 2;            // head of these 4 channels
  int head2 = head * 2;           // float2 offset into pk record
  float y0 = lin_b[lane];
  float y[4] = {y0, y0, y0, y0};
  for (int r = 0; r < 3; r++) {
    const float* __restrict__ hpr = hp + (size_t)r * N_NODES * 64;
    const float* __restrict__ pkr = pk + (size_t)r * N_NODES * 8;
    float4 b1v = *reinterpret_cast<const float4*>(&beta[r * 128 + 64 + cq]);
    float4 hr4[4];
#pragma unroll
    for (int i = 0; i < 4; i++) {
      int n = g * 4 + i;
      n = n < N_NODES ? n : N_NODES - 1;  // tail clamp: duplicate work, store-guarded
      int idxrn = r * N_NODES + n;
      int beg = P[idxrn];
      int end = (idxrn + 1 < RN) ? P[idxrn + 1] : RE;
      float adh = adst[idxrn * 4 + head];
      float4 hpv = *reinterpret_cast<const float4*>(&hpr[n * 64 + cq]);
      float4 oaA = {0.f, 0.f, 0.f, 0.f}, oaB = {0.f, 0.f, 0.f, 0.f};
      float dsA = 0.f, dsB = 0.f, sdA = 0.f, sdB = 0.f;
      int e = beg + slot;
      for (; e + 4 < end; e += 8) {
        EDGE_BODY(e, oaA, dsA, sdA);
        EDGE_BODY(e + 4, oaB, dsB, sdB);
      }
      if (e < end) EDGE_BODY(e, oaA, dsA, sdA);
      float4 oa;
      oa.x = oaA.x + oaB.x;
      oa.y = oaA.y + oaB.y;
      oa.z = oaA.z + oaB.z;
      oa.w = oaA.w + oaB.w;
      float ds = dsA + dsB, sd = sdA + sdB;
      // combine the 4 edge slots (lane bits 4,5)
      oa.x += __shfl_xor(oa.x, 16); oa.x += __shfl_xor(oa.x, 32);
      oa.y += __shfl_xor(oa.y, 16); oa.y += __shfl_xor(oa.y, 32);
      oa.z += __shfl_xor(oa.z, 16); oa.z += __shfl_xor(oa.z, 32);
      oa.w += __shfl_xor(oa.w, 16); oa.w += __shfl_xor(oa.w, 32);
      ds += __shfl_xor(ds, 16); ds += __shfl_xor(ds, 32);
      sd += __shfl_xor(sd, 16); sd += __shfl_xor(sd, 32);
      float inv = 1.f / fmaxf(ds, 1e-20f);
      float4 ov;
      ov.x = oa.x * inv; ov.y = oa.y * inv; ov.z = oa.z * inv; ov.w = oa.w * inv;
      float em = sd / fmaxf((float)(end - beg), 1.f);  // wave-uniform gate es-part
      float gc = ov.x * b1v.x + ov.y * b1v.y + ov.z * b1v.z + ov.w * b1v.w;
      gc += __shfl_xor(gc, 1); gc += __shfl_xor(gc, 2);
      gc += __shfl_xor(gc, 4); gc += __shfl_xor(gc, 8);
      float gt = 1.f / (1.f + __expf(-(gc + em)));
      float4 hrv;
      hrv.x = gt * ov.x + (1.f - gt) * hpv.x;
      hrv.y = gt * ov.y + (1.f - gt) * hpv.y;
      hrv.z = gt * ov.z + (1.f - gt) * hpv.z;
      hrv.w = gt * ov.w + (1.f - gt) * hpv.w;
      hr4[i] = hrv;
    }
    const float* wrow = &sLW[lane * 196 + r * 64];
#pragma unroll
    for (int j4 = 0; j4 < 64; j4 += 4) {
      float4 wv = *reinterpret_cast<const float4*>(wrow + j4);
      const int sl = j4 >> 2;  // lane holding channels j4..j4+3 (words x..w)
#pragma unroll
      for (int i = 0; i < 4; i++) {
        y[i] += bcast(hr4[i].x, sl) * wv.x + bcast(hr4[i].y, sl) * wv.y +
                bcast(hr4[i].z, sl) * wv.z + bcast(hr4[i].w, sl) * wv.w;
      }
    }
  }
#pragma unroll
  for (int i = 0; i < 4; i++) {
    int n = g * 4 + i;
    if (n < N_NODES) out[n * 64 + lane] = y[i];
  }
}

extern "C" void kernel_launch(void* const* d_in, const int* in_sizes, int n_in,
                              void* d_out, int out_size, void* d_ws, size_t ws_size,
                              hipStream_t stream) {
  const float* h = (const float*)d_in[0];
  const int* src = (const int*)d_in[1];
  const int* dst = (const int*)d_in[2];
  const float* d_w = (const float*)d_in[3];
  const float* d_b = (const float*)d_in[4];
  const float* w_w = (const float*)d_in[5];
  const float* w_b = (const float*)d_in[6];
  const float* atten_w = (const float*)d_in[7];
  const float* atten_b = (const float*)d_in[8];
  const float* beta = (const float*)d_in[9];
  const float* lin_w = (const float*)d_in[10];
  const float* lin_b = (const float*)d_in[11];
  float* out = (float*)d_out;

  float* ws = (float*)d_ws;
  float* hp = ws;                                      // R*N*64
  float* pk = hp + (size_t)R_REL * N_NODES * 64;       // R*N*8
  float* adst = pk + (size_t)R_REL * N_NODES * 8;      // R*N*4
  int* P = (int*)(adst + (size_t)R_REL * N_NODES * 4); // RN
  int* ssrc = P + RN;                                  // RE
  unsigned int* rec = (unsigned int*)(ssrc + RE);      // RE
  int* tot = (int*)(rec + RE);                         // K_BKT
  int* BB = tot + K_BKT;                               // K_BKT+1
  int* cursor = BB + K_BKT + 1;                        // K_BKT

  hipMemsetAsync(tot, 0, K_BKT * sizeof(int), stream);
  k_hist<<<NBLK_A, 256, 0, stream>>>(dst, tot);
  k_scanK<<<1, 256, 0, stream>>>(tot, BB, cursor);
  k_scatterA<<<NBLK_A, 256, 0, stream>>>(src, dst, cursor, rec);
  k_bsort<<<K_BKT, 256, 0, stream>>>(rec, BB, P, ssrc);
  k_node<<<1024, 256, 0, stream>>>(h, d_w, d_b, w_w, w_b, atten_w, atten_b, beta,
                                   hp, pk, adst);
  int nfb = (N_NODES + 63) / 64;  // 64 nodes per 1024-thread block
  k_fused<<<nfb, 1024, 0, stream>>>(hp, pk, adst, P, ssrc, beta, lin_w,
                                    lin_b, out);
}

// Round 9
// 595.739 us; speedup vs baseline: 1.5503x; 1.0340x over previous
//
#include <hip/hip_runtime.h>

#define N_NODES 100000
#define N_EDGES 1200000
#define R_REL 3
#define RN (R_REL * N_NODES)   // 300000
#define RE (R_REL * N_EDGES)   // 3600000

// bucket sort params
#define B_BITS 9
#define W_BKT 512                       // nodes per bucket
#define NB_R 196                        // ceil(N_NODES / W_BKT)
#define K_BKT (R_REL * NB_R)            // 588 buckets
#define TILE_A 8192
#define NBLK_A ((RE + TILE_A - 1) / TILE_A)  // 440

__device__ __forceinline__ float bcast(float v, int l) {
  return __int_as_float(__builtin_amdgcn_readlane(__float_as_int(v), l));
}

__device__ __forceinline__ int rel_of(int e) {
  return (e >= 2 * N_EDGES) ? 2 : (e >= N_EDGES ? 1 : 0);
}

// ---------------- CSR build: two-level LDS-staged counting sort ----------------
// Pass 2: exclusive scan of 588 bucket totals -> bucket bases BB + global cursors
__global__ void k_scanK(const int* __restrict__ tot, int* __restrict__ BB,
                        int* __restrict__ cursor) {
  __shared__ int sd[256];
  int t = threadIdx.x;
  int v[3];
  int tots = 0;
#pragma unroll
  for (int q = 0; q < 3; q++) {
    int k = t * 3 + q;
    v[q] = (k < K_BKT) ? tot[k] : 0;
    tots += v[q];
  }
  sd[t] = tots;
  __syncthreads();
  for (int off = 1; off < 256; off <<= 1) {
    int x = (t >= off) ? sd[t - off] : 0;
    __syncthreads();
    sd[t] += x;
    __syncthreads();
  }
  int run = sd[t] - tots;
#pragma unroll
  for (int q = 0; q < 3; q++) {
    int k = t * 3 + q;
    if (k < K_BKT) {
      BB[k] = run;
      cursor[k] = run;
    }
    run += v[q];
  }
  if (t == 255) BB[K_BKT] = RE;
}

__global__ __launch_bounds__(256) void k_scatterA(const int* __restrict__ src,
                                                  const int* __restrict__ dst,
                                                  int* __restrict__ cursor,
                                                  unsigned int* __restrict__ rec) {
  __shared__ int sh[K_BKT];
  int tid = threadIdx.x;
  for (int i = tid; i < K_BKT; i += 256) sh[i] = 0;
  __syncthreads();
  int base = blockIdx.x * TILE_A;
  int end = min(base + TILE_A, RE);
  for (int e = base + tid; e < end; e += 256) {
    atomicAdd(&sh[rel_of(e) * NB_R + (dst[e] >> B_BITS)], 1);
  }
  __syncthreads();
  for (int i = tid; i < K_BKT; i += 256) {
    int c = sh[i];
    sh[i] = c ? atomicAdd(&cursor[i], c) : 0;  // own slot: no cross-thread hazard
  }
  __syncthreads();
  for (int e = base + tid; e < end; e += 256) {
    int d = dst[e];
    int k = rel_of(e) * NB_R + (d >> B_BITS);
    int p = atomicAdd(&sh[k], 1);
    rec[p] = ((unsigned)src[e] << B_BITS) | (unsigned)(d & (W_BKT - 1));
  }
}

__global__ __launch_bounds__(256) void k_bsort(const unsigned int* __restrict__ rec,
                                               const int* __restrict__ BB,
                                               int* __restrict__ P,
                                               int* __restrict__ ssrc) {
  __shared__ int cnt[W_BKT];
  __shared__ int sd[256];
  int kb = blockIdx.x;
  int r = kb / NB_R;
  int nb0 = (kb % NB_R) * W_BKT;  // first node (within relation) of this bucket
  int beg = BB[kb], end = BB[kb + 1];
  int tid = threadIdx.x;
  cnt[tid] = 0;
  cnt[256 + tid] = 0;
  __syncthreads();
  for (int e = beg + tid; e < end; e += 256)
    atomicAdd(&cnt[rec[e] & (W_BKT - 1)], 1);
  __syncthreads();
  // block exclusive scan over 512 (2 elements per thread)
  int v0 = cnt[2 * tid], v1 = cnt[2 * tid + 1];
  int tot2 = v0 + v1;
  sd[tid] = tot2;
  __syncthreads();
  for (int off = 1; off < 256; off <<= 1) {
    int x = (tid >= off) ? sd[tid - off] : 0;
    __syncthreads();
    sd[tid] += x;
    __syncthreads();
  }
  int run = sd[tid] - tot2;
  int node0 = nb0 + 2 * tid;
  int pbase = r * N_NODES + node0;
  if (node0 < N_NODES) P[pbase] = beg + run;
  if (node0 + 1 < N_NODES) P[pbase + 1] = beg + run + v0;
  cnt[2 * tid] = beg + run;
  cnt[2 * tid + 1] = beg + run + v0;
  __syncthreads();
  for (int e = beg + tid; e < end; e += 256) {
    unsigned rc = rec[e];
    int p = atomicAdd(&cnt[rc & (W_BKT - 1)], 1);
    ssrc[p] = (int)(rc >> B_BITS);
  }
}

// ---------------- node transforms (+ fused edge histogram side-job) ----------------
// hp[r][n][64] = h@w_w[r]+w_b[r]
// pk[r][n][8]  = { a0, sdot, a1, sdot, a2, sdot, a3, sdot }
// adst[r][n][4] = per-head dst attention part
// Blocks < NBLK_A additionally compute the 588-bucket edge histogram (k_hist's
// old job) before the GEMM loop -> one fewer serial kernel in the build chain.
__global__ __launch_bounds__(256) void k_node(
    const float* __restrict__ h, const float* __restrict__ d_w,
    const float* __restrict__ d_b, const float* __restrict__ w_w,
    const float* __restrict__ w_b, const float* __restrict__ atten_w,
    const float* __restrict__ atten_b, const float* __restrict__ beta,
    const int* __restrict__ dst, int* __restrict__ tot,
    float* __restrict__ hp, float* __restrict__ pk, float* __restrict__ adst) {
  __shared__ float sW[4 * 4096];  // 64 KB: d_w, w_w[0..2], layout [m][k*64+c]
  __shared__ int shh[K_BKT];      // 2.3 KB: histogram side-job
  int tid = threadIdx.x;
  for (int idx = tid; idx < 4096; idx += 256) {
    sW[idx] = d_w[idx];
    sW[4096 + idx] = w_w[idx];
    sW[8192 + idx] = w_w[4096 + idx];
    sW[12288 + idx] = w_w[8192 + idx];
  }
  if (blockIdx.x < NBLK_A) {  // block-uniform branch: __syncthreads inside is safe
    for (int i = tid; i < K_BKT; i += 256) shh[i] = 0;
    __syncthreads();
    int base = blockIdx.x * TILE_A;
    int end = min(base + TILE_A, RE);
    for (int e = base + tid; e < end; e += 256) {
      atomicAdd(&shh[rel_of(e) * NB_R + (dst[e] >> B_BITS)], 1);
    }
    __syncthreads();
    for (int i = tid; i < K_BKT; i += 256) {
      int c = shh[i];
      if (c) atomicAdd(&tot[i], c);
    }
  }
  __syncthreads();
  int lane = tid & 63, wid = tid >> 6;
  int wave = blockIdx.x * 4 + wid, nw = gridDim.x * 4;
  int k16 = lane & 15, hgrp = lane >> 4;
  float dbv = d_b[lane];
  float wbv0 = w_b[lane], wbv1 = w_b[64 + lane], wbv2 = w_b[128 + lane];
  float wa0[3], wa1[3], wa2[3], ab[3], bb[3];
#pragma unroll
  for (int r = 0; r < 3; r++) {
    wa0[r] = atten_w[r * 48 + k16];
    wa1[r] = atten_w[r * 48 + 16 + k16];
    wa2[r] = atten_w[r * 48 + 32 + k16];
    ab[r] = atten_b[r];
    bb[r] = beta[r * 128 + lane];  // es-part of gate beta
  }
  for (int g = wave; g < N_NODES / 8; g += nw) {
    int n0 = g * 8;
    float hr[8];
#pragma unroll
    for (int i = 0; i < 8; i++) hr[i] = h[(n0 + i) * 64 + lane];
    float acc[8][4];
#pragma unroll
    for (int i = 0; i < 8; i++) {
      acc[i][0] = dbv; acc[i][1] = wbv0; acc[i][2] = wbv1; acc[i][3] = wbv2;
    }
#pragma unroll 4
    for (int k = 0; k < 64; k++) {
      float w0 = sW[k * 64 + lane];
      float w1 = sW[4096 + k * 64 + lane];
      float w2 = sW[8192 + k * 64 + lane];
      float w3 = sW[12288 + k * 64 + lane];
#pragma unroll
      for (int i = 0; i < 8; i++) {
        float a = bcast(hr[i], k);
        acc[i][0] += a * w0; acc[i][1] += a * w1;
        acc[i][2] += a * w2; acc[i][3] += a * w3;
      }
    }
#pragma unroll
    for (int i = 0; i < 8; i++) {
      int n = n0 + i;
      float esv = tanhf(2.f * acc[i][0]);
#pragma unroll
      for (int r = 0; r < 3; r++) {
        int idxrn = r * N_NODES + n;
        float hpv = acc[i][1 + r];
        hp[(size_t)idxrn * 64 + lane] = hpv;
        float cs = hpv * wa0[r] + esv * wa2[r];
        float cd = hpv * wa1[r];
#pragma unroll
        for (int m = 1; m < 16; m <<= 1) {
          cs += __shfl_xor(cs, m);
          cd += __shfl_xor(cd, m);
        }
        float sv = esv * bb[r];
#pragma unroll
        for (int m = 1; m < 64; m <<= 1) sv += __shfl_xor(sv, m);
        if (k16 == 0) {
          float2 rec2 = make_float2(cs + ab[r], sv);
          *reinterpret_cast<float2*>(&pk[(size_t)idxrn * 8 + hgrp * 2]) = rec2;
          adst[(size_t)idxrn * 4 + hgrp] = cd;
        }
      }
    }
  }
}

// ---------------- fused: per-dst softmax-aggregate + gate + final linear ----------------
// 1024-thread blocks; __launch_bounds__(1024, 2): 2 blocks/CU -> 8 waves/SIMD,
// 64-VGPR cap (body fits ~60 -- R8 verified spill-free).
// Epilogue: hr staged in per-wave LDS (slot-0 lanes write), read back with
// UNIFORM-address ds_read_b128 (broadcast, conflict-free) -> removes the
// 256 v_readlane per (r, wave) from the VALU pipe.
#define EDGE_BODY(EE, OA, DS, SD)                                        \
  {                                                                      \
    int s_ = ssrc[EE];                                                   \
    float2 pv_ = *reinterpret_cast<const float2*>(&pkr[s_ * 8 + head2]); \
    float4 hv_ = *reinterpret_cast<const float4*>(&hpr[s_ * 64 + cq]);   \
    float a_ = pv_.x + adh;                                              \
    a_ = a_ >= 0.f ? a_ : 0.01f * a_;                                    \
    float ex_ = __expf(a_);                                              \
    OA.x += ex_ * hv_.x;                                                 \
    OA.y += ex_ * hv_.y;                                                 \
    OA.z += ex_ * hv_.z;                                                 \
    OA.w += ex_ * hv_.w;                                                 \
    DS += ex_;                                                           \
    SD += pv_.y;                                                         \
  }

__global__ __launch_bounds__(1024, 2) void k_fused(
    const float* __restrict__ hp, const float* __restrict__ pk,
    const float* __restrict__ adst, const int* __restrict__ P,
    const int* __restrict__ ssrc, const float* __restrict__ beta,
    const float* __restrict__ lin_w, const float* __restrict__ lin_b,
    float* __restrict__ out) {
  __shared__ __align__(16) float sLW[64 * 196];   // transposed lin_w: [c][j], stride 196
  __shared__ __align__(16) float sHR[16][4][64];  // per-wave hr staging (16 KB)
  int tid = threadIdx.x;
  for (int idx = tid; idx < 192 * 64; idx += 1024) {
    int j = idx >> 6, c = idx & 63;
    sLW[c * 196 + j] = lin_w[idx];
  }
  __syncthreads();
  int lane = tid & 63, wid = tid >> 6;
  int g = blockIdx.x * 16 + wid;  // 4 nodes per wave
  int slot = lane >> 4;           // edge slot 0..3
  int c16 = lane & 15;            // channel-quad index
  int cq = c16 * 4;               // first channel of this lane's quad
  int head = c16 >> 2;            // head of these 4 channels
  int head2 = head * 2;           // float2 offset into pk record
  float y0 = lin_b[lane];
  float y[4] = {y0, y0, y0, y0};
  for (int r = 0; r < 3; r++) {
    const float* __restrict__ hpr = hp + (size_t)r * N_NODES * 64;
    const float* __restrict__ pkr = pk + (size_t)r * N_NODES * 8;
    float4 b1v = *reinterpret_cast<const float4*>(&beta[r * 128 + 64 + cq]);
#pragma unroll
    for (int i = 0; i < 4; i++) {
      int n = g * 4 + i;
      n = n < N_NODES ? n : N_NODES - 1;  // tail clamp: duplicate work, store-guarded
      int idxrn = r * N_NODES + n;
      int beg = P[idxrn];
      int end = (idxrn + 1 < RN) ? P[idxrn + 1] : RE;
      float adh = adst[idxrn * 4 + head];
      float4 hpv = *reinterpret_cast<const float4*>(&hpr[n * 64 + cq]);
      float4 oaA = {0.f, 0.f, 0.f, 0.f}, oaB = {0.f, 0.f, 0.f, 0.f};
      float dsA = 0.f, dsB = 0.f, sdA = 0.f, sdB = 0.f;
      int e = beg + slot;
      for (; e + 4 < end; e += 8) {
        EDGE_BODY(e, oaA, dsA, sdA);
        EDGE_BODY(e + 4, oaB, dsB, sdB);
      }
      if (e < end) EDGE_BODY(e, oaA, dsA, sdA);
      float4 oa;
      oa.x = oaA.x + oaB.x;
      oa.y = oaA.y + oaB.y;
      oa.z = oaA.z + oaB.z;
      oa.w = oaA.w + oaB.w;
      float ds = dsA + dsB, sd = sdA + sdB;
      // combine the 4 edge slots (lane bits 4,5)
      oa.x += __shfl_xor(oa.x, 16); oa.x += __shfl_xor(oa.x, 32);
      oa.y += __shfl_xor(oa.y, 16); oa.y += __shfl_xor(oa.y, 32);
      oa.z += __shfl_xor(oa.z, 16); oa.z += __shfl_xor(oa.z, 32);
      oa.w += __shfl_xor(oa.w, 16); oa.w += __shfl_xor(oa.w, 32);
      ds += __shfl_xor(ds, 16); ds += __shfl_xor(ds, 32);
      sd += __shfl_xor(sd, 16); sd += __shfl_xor(sd, 32);
      float inv = 1.f / fmaxf(ds, 1e-20f);
      float4 ov;
      ov.x = oa.x * inv; ov.y = oa.y * inv; ov.z = oa.z * inv; ov.w = oa.w * inv;
      float em = sd / fmaxf((float)(end - beg), 1.f);  // wave-uniform gate es-part
      float gc = ov.x * b1v.x + ov.y * b1v.y + ov.z * b1v.z + ov.w * b1v.w;
      gc += __shfl_xor(gc, 1); gc += __shfl_xor(gc, 2);
      gc += __shfl_xor(gc, 4); gc += __shfl_xor(gc, 8);
      float gt = 1.f / (1.f + __expf(-(gc + em)));
      float4 hrv;
      hrv.x = gt * ov.x + (1.f - gt) * hpv.x;
      hrv.y = gt * ov.y + (1.f - gt) * hpv.y;
      hrv.z = gt * ov.z + (1.f - gt) * hpv.z;
      hrv.w = gt * ov.w + (1.f - gt) * hpv.w;
      if (slot == 0) *reinterpret_cast<float4*>(&sHR[wid][i][cq]) = hrv;
    }
    __builtin_amdgcn_wave_barrier();  // keep LDS write->read order (no cost)
    const float* wrow = &sLW[lane * 196 + r * 64];
    const float* hrow = &sHR[wid][0][0];
#pragma unroll
    for (int j4 = 0; j4 < 64; j4 += 4) {
      float4 wv = *reinterpret_cast<const float4*>(wrow + j4);
#pragma unroll
      for (int i = 0; i < 4; i++) {
        // uniform address across lanes -> LDS broadcast, no conflict, no VALU
        float4 hv = *reinterpret_cast<const float4*>(hrow + i * 64 + j4);
        y[i] += hv.x * wv.x + hv.y * wv.y + hv.z * wv.z + hv.w * wv.w;
      }
    }
    __builtin_amdgcn_wave_barrier();  // reads done before next r overwrites sHR
  }
#pragma unroll
  for (int i = 0; i < 4; i++) {
    int n = g * 4 + i;
    if (n < N_NODES) out[n * 64 + lane] = y[i];
  }
}

extern "C" void kernel_launch(void* const* d_in, const int* in_sizes, int n_in,
                              void* d_out, int out_size, void* d_ws, size_t ws_size,
                              hipStream_t stream) {
  const float* h = (const float*)d_in[0];
  const int* src = (const int*)d_in[1];
  const int* dst = (const int*)d_in[2];
  const float* d_w = (const float*)d_in[3];
  const float* d_b = (const float*)d_in[4];
  const float* w_w = (const float*)d_in[5];
  const float* w_b = (const float*)d_in[6];
  const float* atten_w = (const float*)d_in[7];
  const float* atten_b = (const float*)d_in[8];
  const float* beta = (const float*)d_in[9];
  const float* lin_w = (const float*)d_in[10];
  const float* lin_b = (const float*)d_in[11];
  float* out = (float*)d_out;

  float* ws = (float*)d_ws;
  float* hp = ws;                                      // R*N*64
  float* pk = hp + (size_t)R_REL * N_NODES * 64;       // R*N*8
  float* adst = pk + (size_t)R_REL * N_NODES * 8;      // R*N*4
  int* P = (int*)(adst + (size_t)R_REL * N_NODES * 4); // RN
  int* ssrc = P + RN;                                  // RE
  unsigned int* rec = (unsigned int*)(ssrc + RE);      // RE
  int* tot = (int*)(rec + RE);                         // K_BKT
  int* BB = tot + K_BKT;                               // K_BKT+1
  int* cursor = BB + K_BKT + 1;                        // K_BKT

  hipMemsetAsync(tot, 0, K_BKT * sizeof(int), stream);
  k_node<<<1024, 256, 0, stream>>>(h, d_w, d_b, w_w, w_b, atten_w, atten_b, beta,
                                   dst, tot, hp, pk, adst);
  k_scanK<<<1, 256, 0, stream>>>(tot, BB, cursor);
  k_scatterA<<<NBLK_A, 256, 0, stream>>>(src, dst, cursor, rec);
  k_bsort<<<K_BKT, 256, 0, stream>>>(rec, BB, P, ssrc);
  int nfb = (N_NODES + 63) / 64;  // 64 nodes per 1024-thread block
  k_fused<<<nfb, 1024, 0, stream>>>(hp, pk, adst, P, ssrc, beta, lin_w,
                                    lin_b, out);
}

// Round 10
// 594.512 us; speedup vs baseline: 1.5535x; 1.0021x over previous
//
#include <hip/hip_runtime.h>

#define N_NODES 100000
#define N_EDGES 1200000
#define R_REL 3
#define RN (R_REL * N_NODES)   // 300000
#define RE (R_REL * N_EDGES)   // 3600000

// bucket sort params
#define B_BITS 9
#define W_BKT 512                       // nodes per bucket
#define NB_R 196                        // ceil(N_NODES / W_BKT)
#define K_BKT (R_REL * NB_R)            // 588 buckets
#define TILE_A 8192
#define NBLK_A ((RE + TILE_A - 1) / TILE_A)  // 440

typedef _Float16 half4v __attribute__((ext_vector_type(4)));

__device__ __forceinline__ float bcast(float v, int l) {
  return __int_as_float(__builtin_amdgcn_readlane(__float_as_int(v), l));
}

__device__ __forceinline__ int rel_of(int e) {
  return (e >= 2 * N_EDGES) ? 2 : (e >= N_EDGES ? 1 : 0);
}

// ---------------- CSR build: two-level LDS-staged counting sort ----------------
// Pass 2: exclusive scan of 588 bucket totals -> bucket bases BB + global cursors
__global__ void k_scanK(const int* __restrict__ tot, int* __restrict__ BB,
                        int* __restrict__ cursor) {
  __shared__ int sd[256];
  int t = threadIdx.x;
  int v[3];
  int tots = 0;
#pragma unroll
  for (int q = 0; q < 3; q++) {
    int k = t * 3 + q;
    v[q] = (k < K_BKT) ? tot[k] : 0;
    tots += v[q];
  }
  sd[t] = tots;
  __syncthreads();
  for (int off = 1; off < 256; off <<= 1) {
    int x = (t >= off) ? sd[t - off] : 0;
    __syncthreads();
    sd[t] += x;
    __syncthreads();
  }
  int run = sd[t] - tots;
#pragma unroll
  for (int q = 0; q < 3; q++) {
    int k = t * 3 + q;
    if (k < K_BKT) {
      BB[k] = run;
      cursor[k] = run;
    }
    run += v[q];
  }
  if (t == 255) BB[K_BKT] = RE;
}

__global__ __launch_bounds__(256) void k_scatterA(const int* __restrict__ src,
                                                  const int* __restrict__ dst,
                                                  int* __restrict__ cursor,
                                                  unsigned int* __restrict__ rec) {
  __shared__ int sh[K_BKT];
  int tid = threadIdx.x;
  for (int i = tid; i < K_BKT; i += 256) sh[i] = 0;
  __syncthreads();
  int base = blockIdx.x * TILE_A;
  int end = min(base + TILE_A, RE);
  for (int e = base + tid; e < end; e += 256) {
    atomicAdd(&sh[rel_of(e) * NB_R + (dst[e] >> B_BITS)], 1);
  }
  __syncthreads();
  for (int i = tid; i < K_BKT; i += 256) {
    int c = sh[i];
    sh[i] = c ? atomicAdd(&cursor[i], c) : 0;  // own slot: no cross-thread hazard
  }
  __syncthreads();
  for (int e = base + tid; e < end; e += 256) {
    int d = dst[e];
    int k = rel_of(e) * NB_R + (d >> B_BITS);
    int p = atomicAdd(&sh[k], 1);
    rec[p] = ((unsigned)src[e] << B_BITS) | (unsigned)(d & (W_BKT - 1));
  }
}

__global__ __launch_bounds__(256) void k_bsort(const unsigned int* __restrict__ rec,
                                               const int* __restrict__ BB,
                                               int* __restrict__ P,
                                               int* __restrict__ ssrc) {
  __shared__ int cnt[W_BKT];
  __shared__ int sd[256];
  int kb = blockIdx.x;
  int r = kb / NB_R;
  int nb0 = (kb % NB_R) * W_BKT;  // first node (within relation) of this bucket
  int beg = BB[kb], end = BB[kb + 1];
  int tid = threadIdx.x;
  cnt[tid] = 0;
  cnt[256 + tid] = 0;
  __syncthreads();
  for (int e = beg + tid; e < end; e += 256)
    atomicAdd(&cnt[rec[e] & (W_BKT - 1)], 1);
  __syncthreads();
  // block exclusive scan over 512 (2 elements per thread)
  int v0 = cnt[2 * tid], v1 = cnt[2 * tid + 1];
  int tot2 = v0 + v1;
  sd[tid] = tot2;
  __syncthreads();
  for (int off = 1; off < 256; off <<= 1) {
    int x = (tid >= off) ? sd[tid - off] : 0;
    __syncthreads();
    sd[tid] += x;
    __syncthreads();
  }
  int run = sd[tid] - tot2;
  int node0 = nb0 + 2 * tid;
  int pbase = r * N_NODES + node0;
  if (node0 < N_NODES) P[pbase] = beg + run;
  if (node0 + 1 < N_NODES) P[pbase + 1] = beg + run + v0;
  cnt[2 * tid] = beg + run;
  cnt[2 * tid + 1] = beg + run + v0;
  __syncthreads();
  for (int e = beg + tid; e < end; e += 256) {
    unsigned rc = rec[e];
    int p = atomicAdd(&cnt[rc & (W_BKT - 1)], 1);
    ssrc[p] = (int)(rc >> B_BITS);
  }
}

// ---------------- node transforms (+ fused edge histogram side-job) ----------------
// hp16[r][n][64] = h@w_w[r]+w_b[r]  stored FP16 (halves gather lines in k_fused;
//   precision: |hp|<~2, fp16 rel err 2^-11 -> <=1e-3 tail, inside 2^-9 tolerance)
// pk[r][n][8]  = { a0, sdot, a1, sdot, a2, sdot, a3, sdot }  (f32)
// adst[r][n][4] = per-head dst attention part
__global__ __launch_bounds__(256) void k_node(
    const float* __restrict__ h, const float* __restrict__ d_w,
    const float* __restrict__ d_b, const float* __restrict__ w_w,
    const float* __restrict__ w_b, const float* __restrict__ atten_w,
    const float* __restrict__ atten_b, const float* __restrict__ beta,
    const int* __restrict__ dst, int* __restrict__ tot,
    _Float16* __restrict__ hp16, float* __restrict__ pk,
    float* __restrict__ adst) {
  __shared__ float sW[4 * 4096];  // 64 KB: d_w, w_w[0..2], layout [m][k*64+c]
  __shared__ int shh[K_BKT];      // 2.3 KB: histogram side-job
  int tid = threadIdx.x;
  for (int idx = tid; idx < 4096; idx += 256) {
    sW[idx] = d_w[idx];
    sW[4096 + idx] = w_w[idx];
    sW[8192 + idx] = w_w[4096 + idx];
    sW[12288 + idx] = w_w[8192 + idx];
  }
  if (blockIdx.x < NBLK_A) {  // block-uniform branch: __syncthreads inside is safe
    for (int i = tid; i < K_BKT; i += 256) shh[i] = 0;
    __syncthreads();
    int base = blockIdx.x * TILE_A;
    int end = min(base + TILE_A, RE);
    for (int e = base + tid; e < end; e += 256) {
      atomicAdd(&shh[rel_of(e) * NB_R + (dst[e] >> B_BITS)], 1);
    }
    __syncthreads();
    for (int i = tid; i < K_BKT; i += 256) {
      int c = shh[i];
      if (c) atomicAdd(&tot[i], c);
    }
  }
  __syncthreads();
  int lane = tid & 63, wid = tid >> 6;
  int wave = blockIdx.x * 4 + wid, nw = gridDim.x * 4;
  int k16 = lane & 15, hgrp = lane >> 4;
  float dbv = d_b[lane];
  float wbv0 = w_b[lane], wbv1 = w_b[64 + lane], wbv2 = w_b[128 + lane];
  float wa0[3], wa1[3], wa2[3], ab[3], bb[3];
#pragma unroll
  for (int r = 0; r < 3; r++) {
    wa0[r] = atten_w[r * 48 + k16];
    wa1[r] = atten_w[r * 48 + 16 + k16];
    wa2[r] = atten_w[r * 48 + 32 + k16];
    ab[r] = atten_b[r];
    bb[r] = beta[r * 128 + lane];  // es-part of gate beta
  }
  for (int g = wave; g < N_NODES / 8; g += nw) {
    int n0 = g * 8;
    float hr[8];
#pragma unroll
    for (int i = 0; i < 8; i++) hr[i] = h[(n0 + i) * 64 + lane];
    float acc[8][4];
#pragma unroll
    for (int i = 0; i < 8; i++) {
      acc[i][0] = dbv; acc[i][1] = wbv0; acc[i][2] = wbv1; acc[i][3] = wbv2;
    }
#pragma unroll 4
    for (int k = 0; k < 64; k++) {
      float w0 = sW[k * 64 + lane];
      float w1 = sW[4096 + k * 64 + lane];
      float w2 = sW[8192 + k * 64 + lane];
      float w3 = sW[12288 + k * 64 + lane];
#pragma unroll
      for (int i = 0; i < 8; i++) {
        float a = bcast(hr[i], k);
        acc[i][0] += a * w0; acc[i][1] += a * w1;
        acc[i][2] += a * w2; acc[i][3] += a * w3;
      }
    }
#pragma unroll
    for (int i = 0; i < 8; i++) {
      int n = n0 + i;
      float esv = tanhf(2.f * acc[i][0]);
#pragma unroll
      for (int r = 0; r < 3; r++) {
        int idxrn = r * N_NODES + n;
        float hpv = acc[i][1 + r];
        hp16[(size_t)idxrn * 64 + lane] = (_Float16)hpv;
        float cs = hpv * wa0[r] + esv * wa2[r];
        float cd = hpv * wa1[r];
#pragma unroll
        for (int m = 1; m < 16; m <<= 1) {
          cs += __shfl_xor(cs, m);
          cd += __shfl_xor(cd, m);
        }
        float sv = esv * bb[r];
#pragma unroll
        for (int m = 1; m < 64; m <<= 1) sv += __shfl_xor(sv, m);
        if (k16 == 0) {
          float2 rec2 = make_float2(cs + ab[r], sv);
          *reinterpret_cast<float2*>(&pk[(size_t)idxrn * 8 + hgrp * 2]) = rec2;
          adst[(size_t)idxrn * 4 + hgrp] = cd;
        }
      }
    }
  }
}

// ---------------- fused: per-dst softmax-aggregate + gate + final linear ----------------
// 1024-thread blocks; __launch_bounds__(1024, 2): 2 blocks/CU -> 8 waves/SIMD,
// 64-VGPR cap (R8/R9 verified spill-free at 60 VGPR).
// hp gathered as FP16: 2 cache lines/edge instead of 4 (lines/edge 5 -> 3);
// ex*hv compiles to v_fma_mix_f32 so fp16->f32 conversion is free.
#define EDGE_BODY(EE, OA, DS, SD)                                          \
  {                                                                        \
    int s_ = ssrc[EE];                                                     \
    float2 pv_ = *reinterpret_cast<const float2*>(&pkr[s_ * 8 + head2]);   \
    half4v hv_ = *reinterpret_cast<const half4v*>(&hpr16[s_ * 64 + cq]);   \
    float a_ = pv_.x + adh;                                                \
    a_ = a_ >= 0.f ? a_ : 0.01f * a_;                                      \
    float ex_ = __expf(a_);                                                \
    OA.x += ex_ * (float)hv_.x;                                            \
    OA.y += ex_ * (float)hv_.y;                                            \
    OA.z += ex_ * (float)hv_.z;                                            \
    OA.w += ex_ * (float)hv_.w;                                            \
    DS += ex_;                                                             \
    SD += pv_.y;                                                           \
  }

__global__ __launch_bounds__(1024, 2) void k_fused(
    const _Float16* __restrict__ hp16, const float* __restrict__ pk,
    const float* __restrict__ adst, const int* __restrict__ P,
    const int* __restrict__ ssrc, const float* __restrict__ beta,
    const float* __restrict__ lin_w, const float* __restrict__ lin_b,
    float* __restrict__ out) {
  __shared__ __align__(16) float sLW[64 * 196];   // transposed lin_w: [c][j], stride 196
  __shared__ __align__(16) float sHR[16][4][64];  // per-wave hr staging (16 KB)
  int tid = threadIdx.x;
  for (int idx = tid; idx < 192 * 64; idx += 1024) {
    int j = idx >> 6, c = idx & 63;
    sLW[c * 196 + j] = lin_w[idx];
  }
  __syncthreads();
  int lane = tid & 63, wid = tid >> 6;
  int g = blockIdx.x * 16 + wid;  // 4 nodes per wave
  int slot = lane >> 4;           // edge slot 0..3
  int c16 = lane & 15;            // channel-quad index
  int cq = c16 * 4;               // first channel of this lane's quad
  int head = c16 >> 2;            // head of these 4 channels
  int head2 = head * 2;           // float2 offset into pk record
  float y0 = lin_b[lane];
  float y[4] = {y0, y0, y0, y0};
  for (int r = 0; r < 3; r++) {
    const _Float16* __restrict__ hpr16 = hp16 + (size_t)r * N_NODES * 64;
    const float* __restrict__ pkr = pk + (size_t)r * N_NODES * 8;
    float4 b1v = *reinterpret_cast<const float4*>(&beta[r * 128 + 64 + cq]);
#pragma unroll
    for (int i = 0; i < 4; i++) {
      int n = g * 4 + i;
      n = n < N_NODES ? n : N_NODES - 1;  // tail clamp: duplicate work, store-guarded
      int idxrn = r * N_NODES + n;
      int beg = P[idxrn];
      int end = (idxrn + 1 < RN) ? P[idxrn + 1] : RE;
      float adh = adst[idxrn * 4 + head];
      half4v hq_ = *reinterpret_cast<const half4v*>(&hpr16[n * 64 + cq]);
      float4 hpv = make_float4((float)hq_.x, (float)hq_.y, (float)hq_.z,
                               (float)hq_.w);
      float4 oaA = {0.f, 0.f, 0.f, 0.f}, oaB = {0.f, 0.f, 0.f, 0.f};
      float dsA = 0.f, dsB = 0.f, sdA = 0.f, sdB = 0.f;
      int e = beg + slot;
      for (; e + 4 < end; e += 8) {
        EDGE_BODY(e, oaA, dsA, sdA);
        EDGE_BODY(e + 4, oaB, dsB, sdB);
      }
      if (e < end) EDGE_BODY(e, oaA, dsA, sdA);
      float4 oa;
      oa.x = oaA.x + oaB.x;
      oa.y = oaA.y + oaB.y;
      oa.z = oaA.z + oaB.z;
      oa.w = oaA.w + oaB.w;
      float ds = dsA + dsB, sd = sdA + sdB;
      // combine the 4 edge slots (lane bits 4,5)
      oa.x += __shfl_xor(oa.x, 16); oa.x += __shfl_xor(oa.x, 32);
      oa.y += __shfl_xor(oa.y, 16); oa.y += __shfl_xor(oa.y, 32);
      oa.z += __shfl_xor(oa.z, 16); oa.z += __shfl_xor(oa.z, 32);
      oa.w += __shfl_xor(oa.w, 16); oa.w += __shfl_xor(oa.w, 32);
      ds += __shfl_xor(ds, 16); ds += __shfl_xor(ds, 32);
      sd += __shfl_xor(sd, 16); sd += __shfl_xor(sd, 32);
      float inv = 1.f / fmaxf(ds, 1e-20f);
      float4 ov;
      ov.x = oa.x * inv; ov.y = oa.y * inv; ov.z = oa.z * inv; ov.w = oa.w * inv;
      float em = sd / fmaxf((float)(end - beg), 1.f);  // wave-uniform gate es-part
      float gc = ov.x * b1v.x + ov.y * b1v.y + ov.z * b1v.z + ov.w * b1v.w;
      gc += __shfl_xor(gc, 1); gc += __shfl_xor(gc, 2);
      gc += __shfl_xor(gc, 4); gc += __shfl_xor(gc, 8);
      float gt = 1.f / (1.f + __expf(-(gc + em)));
      float4 hrv;
      hrv.x = gt * ov.x + (1.f - gt) * hpv.x;
      hrv.y = gt * ov.y + (1.f - gt) * hpv.y;
      hrv.z = gt * ov.z + (1.f - gt) * hpv.z;
      hrv.w = gt * ov.w + (1.f - gt) * hpv.w;
      if (slot == 0) *reinterpret_cast<float4*>(&sHR[wid][i][cq]) = hrv;
    }
    __builtin_amdgcn_wave_barrier();  // keep LDS write->read order (no cost)
    const float* wrow = &sLW[lane * 196 + r * 64];
    const float* hrow = &sHR[wid][0][0];
#pragma unroll
    for (int j4 = 0; j4 < 64; j4 += 4) {
      float4 wv = *reinterpret_cast<const float4*>(wrow + j4);
#pragma unroll
      for (int i = 0; i < 4; i++) {
        // uniform address across lanes -> LDS broadcast, no conflict, no VALU
        float4 hv = *reinterpret_cast<const float4*>(hrow + i * 64 + j4);
        y[i] += hv.x * wv.x + hv.y * wv.y + hv.z * wv.z + hv.w * wv.w;
      }
    }
    __builtin_amdgcn_wave_barrier();  // reads done before next r overwrites sHR
  }
#pragma unroll
  for (int i = 0; i < 4; i++) {
    int n = g * 4 + i;
    if (n < N_NODES) out[n * 64 + lane] = y[i];
  }
}

extern "C" void kernel_launch(void* const* d_in, const int* in_sizes, int n_in,
                              void* d_out, int out_size, void* d_ws, size_t ws_size,
                              hipStream_t stream) {
  const float* h = (const float*)d_in[0];
  const int* src = (const int*)d_in[1];
  const int* dst = (const int*)d_in[2];
  const float* d_w = (const float*)d_in[3];
  const float* d_b = (const float*)d_in[4];
  const float* w_w = (const float*)d_in[5];
  const float* w_b = (const float*)d_in[6];
  const float* atten_w = (const float*)d_in[7];
  const float* atten_b = (const float*)d_in[8];
  const float* beta = (const float*)d_in[9];
  const float* lin_w = (const float*)d_in[10];
  const float* lin_b = (const float*)d_in[11];
  float* out = (float*)d_out;

  _Float16* hp16 = (_Float16*)d_ws;                    // R*N*64 halves (38.4 MB)
  float* pk = (float*)(hp16 + (size_t)RN * 64);        // R*N*8
  float* adst = pk + (size_t)RN * 8;                   // R*N*4
  int* P = (int*)(adst + (size_t)RN * 4);              // RN
  int* ssrc = P + RN;                                  // RE
  unsigned int* rec = (unsigned int*)(ssrc + RE);      // RE
  int* tot = (int*)(rec + RE);                         // K_BKT
  int* BB = tot + K_BKT;                               // K_BKT+1
  int* cursor = BB + K_BKT + 1;                        // K_BKT

  hipMemsetAsync(tot, 0, K_BKT * sizeof(int), stream);
  k_node<<<1024, 256, 0, stream>>>(h, d_w, d_b, w_w, w_b, atten_w, atten_b, beta,
                                   dst, tot, hp16, pk, adst);
  k_scanK<<<1, 256, 0, stream>>>(tot, BB, cursor);
  k_scatterA<<<NBLK_A, 256, 0, stream>>>(src, dst, cursor, rec);
  k_bsort<<<K_BKT, 256, 0, stream>>>(rec, BB, P, ssrc);
  int nfb = (N_NODES + 63) / 64;  // 64 nodes per 1024-thread block
  k_fused<<<nfb, 1024, 0, stream>>>(hp16, pk, adst, P, ssrc, beta, lin_w,
                                    lin_b, out);
}

// Round 11
// 580.856 us; speedup vs baseline: 1.5900x; 1.0235x over previous
//
#include <hip/hip_runtime.h>

#define N_NODES 100000
#define N_EDGES 1200000
#define R_REL 3
#define RN (R_REL * N_NODES)   // 300000
#define RE (R_REL * N_EDGES)   // 3600000

// bucket sort params
#define B_BITS 9
#define W_BKT 512                       // nodes per bucket
#define NB_R 196                        // ceil(N_NODES / W_BKT)
#define K_BKT (R_REL * NB_R)            // 588 buckets
#define TILE_A 8192
#define NBLK_A ((RE + TILE_A - 1) / TILE_A)  // 440
#define NODE_BLKS 1024                  // node-role blocks in k_nb

typedef _Float16 half4v __attribute__((ext_vector_type(4)));

__device__ __forceinline__ float bcast(float v, int l) {
  return __int_as_float(__builtin_amdgcn_readlane(__float_as_int(v), l));
}

__device__ __forceinline__ int rel_of(int e) {
  return (e >= 2 * N_EDGES) ? 2 : (e >= N_EDGES ? 1 : 0);
}

// ---------------- CSR build: two-level LDS-staged counting sort ----------------
// Pass 1: per-tile LDS histogram over 588 coarse buckets -> global totals.
// Standalone (was fused into k_node) so that k_node no longer gates the
// scanK -> scatterA chain and can instead overlap with bsort (k_nb below).
__global__ __launch_bounds__(256) void k_hist(const int* __restrict__ dst,
                                              int* __restrict__ tot) {
  __shared__ int sh[K_BKT];
  int tid = threadIdx.x;
  for (int i = tid; i < K_BKT; i += 256) sh[i] = 0;
  __syncthreads();
  int base = blockIdx.x * TILE_A;
  int end = min(base + TILE_A, RE);
  for (int e = base + tid; e < end; e += 256) {
    atomicAdd(&sh[rel_of(e) * NB_R + (dst[e] >> B_BITS)], 1);
  }
  __syncthreads();
  for (int i = tid; i < K_BKT; i += 256) {
    int c = sh[i];
    if (c) atomicAdd(&tot[i], c);
  }
}

// Pass 2: exclusive scan of 588 bucket totals -> bucket bases BB + global cursors
__global__ void k_scanK(const int* __restrict__ tot, int* __restrict__ BB,
                        int* __restrict__ cursor) {
  __shared__ int sd[256];
  int t = threadIdx.x;
  int v[3];
  int tots = 0;
#pragma unroll
  for (int q = 0; q < 3; q++) {
    int k = t * 3 + q;
    v[q] = (k < K_BKT) ? tot[k] : 0;
    tots += v[q];
  }
  sd[t] = tots;
  __syncthreads();
  for (int off = 1; off < 256; off <<= 1) {
    int x = (t >= off) ? sd[t - off] : 0;
    __syncthreads();
    sd[t] += x;
    __syncthreads();
  }
  int run = sd[t] - tots;
#pragma unroll
  for (int q = 0; q < 3; q++) {
    int k = t * 3 + q;
    if (k < K_BKT) {
      BB[k] = run;
      cursor[k] = run;
    }
    run += v[q];
  }
  if (t == 255) BB[K_BKT] = RE;
}

__global__ __launch_bounds__(256) void k_scatterA(const int* __restrict__ src,
                                                  const int* __restrict__ dst,
                                                  int* __restrict__ cursor,
                                                  unsigned int* __restrict__ rec) {
  __shared__ int sh[K_BKT];
  int tid = threadIdx.x;
  for (int i = tid; i < K_BKT; i += 256) sh[i] = 0;
  __syncthreads();
  int base = blockIdx.x * TILE_A;
  int end = min(base + TILE_A, RE);
  for (int e = base + tid; e < end; e += 256) {
    atomicAdd(&sh[rel_of(e) * NB_R + (dst[e] >> B_BITS)], 1);
  }
  __syncthreads();
  for (int i = tid; i < K_BKT; i += 256) {
    int c = sh[i];
    sh[i] = c ? atomicAdd(&cursor[i], c) : 0;  // own slot: no cross-thread hazard
  }
  __syncthreads();
  for (int e = base + tid; e < end; e += 256) {
    int d = dst[e];
    int k = rel_of(e) * NB_R + (d >> B_BITS);
    int p = atomicAdd(&sh[k], 1);
    rec[p] = ((unsigned)src[e] << B_BITS) | (unsigned)(d & (W_BKT - 1));
  }
}

// ---------------- merged kernel: bsort blocks + node-transform blocks ----------------
// Blocks [0, K_BKT): per-bucket counting sort -> P + ssrc   (depends on rec/BB)
// Blocks [K_BKT, K_BKT+NODE_BLKS): node transforms          (independent)
// The two roles have no cross-dependency; co-scheduling them makes wall time
// ~max of the two instead of their sum. LDS = 64KB (sW) + 3KB (cnt/sd) = 67KB
// -> 2 blocks/CU, same as the old k_node.
// Node role outputs:
//   hp16[r][n][64] = h@w_w[r]+w_b[r]  stored FP16
//   pk[r][n][8]  = { a0, sdot, a1, sdot, a2, sdot, a3, sdot }  (f32)
//   adst[r][n][4] = per-head dst attention part
__global__ __launch_bounds__(256) void k_nb(
    const unsigned int* __restrict__ rec, const int* __restrict__ BB,
    int* __restrict__ P, int* __restrict__ ssrc,
    const float* __restrict__ h, const float* __restrict__ d_w,
    const float* __restrict__ d_b, const float* __restrict__ w_w,
    const float* __restrict__ w_b, const float* __restrict__ atten_w,
    const float* __restrict__ atten_b, const float* __restrict__ beta,
    _Float16* __restrict__ hp16, float* __restrict__ pk,
    float* __restrict__ adst) {
  __shared__ float sW[4 * 4096];  // 64 KB: d_w, w_w[0..2] (node role)
  __shared__ int cnt[W_BKT];      // 2 KB (bsort role)
  __shared__ int sdx[256];        // 1 KB (bsort role)
  int tid = threadIdx.x;
  if (blockIdx.x < K_BKT) {
    // ---------------- bsort role ----------------
    int kb = blockIdx.x;
    int r = kb / NB_R;
    int nb0 = (kb % NB_R) * W_BKT;
    int beg = BB[kb], end = BB[kb + 1];
    cnt[tid] = 0;
    cnt[256 + tid] = 0;
    __syncthreads();
    for (int e = beg + tid; e < end; e += 256)
      atomicAdd(&cnt[rec[e] & (W_BKT - 1)], 1);
    __syncthreads();
    int v0 = cnt[2 * tid], v1 = cnt[2 * tid + 1];
    int tot2 = v0 + v1;
    sdx[tid] = tot2;
    __syncthreads();
    for (int off = 1; off < 256; off <<= 1) {
      int x = (tid >= off) ? sdx[tid - off] : 0;
      __syncthreads();
      sdx[tid] += x;
      __syncthreads();
    }
    int run = sdx[tid] - tot2;
    int node0 = nb0 + 2 * tid;
    int pbase = r * N_NODES + node0;
    if (node0 < N_NODES) P[pbase] = beg + run;
    if (node0 + 1 < N_NODES) P[pbase + 1] = beg + run + v0;
    cnt[2 * tid] = beg + run;
    cnt[2 * tid + 1] = beg + run + v0;
    __syncthreads();
    for (int e = beg + tid; e < end; e += 256) {
      unsigned rc = rec[e];
      int p = atomicAdd(&cnt[rc & (W_BKT - 1)], 1);
      ssrc[p] = (int)(rc >> B_BITS);
    }
    return;
  }
  // ---------------- node role ----------------
  int nbid = blockIdx.x - K_BKT;
  for (int idx = tid; idx < 4096; idx += 256) {
    sW[idx] = d_w[idx];
    sW[4096 + idx] = w_w[idx];
    sW[8192 + idx] = w_w[4096 + idx];
    sW[12288 + idx] = w_w[8192 + idx];
  }
  __syncthreads();
  int lane = tid & 63, wid = tid >> 6;
  int wave = nbid * 4 + wid, nw = NODE_BLKS * 4;
  int k16 = lane & 15, hgrp = lane >> 4;
  float dbv = d_b[lane];
  float wbv0 = w_b[lane], wbv1 = w_b[64 + lane], wbv2 = w_b[128 + lane];
  float wa0[3], wa1[3], wa2[3], ab[3], bb[3];
#pragma unroll
  for (int r = 0; r < 3; r++) {
    wa0[r] = atten_w[r * 48 + k16];
    wa1[r] = atten_w[r * 48 + 16 + k16];
    wa2[r] = atten_w[r * 48 + 32 + k16];
    ab[r] = atten_b[r];
    bb[r] = beta[r * 128 + lane];  // es-part of gate beta
  }
  for (int g = wave; g < N_NODES / 8; g += nw) {
    int n0 = g * 8;
    float hr[8];
#pragma unroll
    for (int i = 0; i < 8; i++) hr[i] = h[(n0 + i) * 64 + lane];
    float acc[8][4];
#pragma unroll
    for (int i = 0; i < 8; i++) {
      acc[i][0] = dbv; acc[i][1] = wbv0; acc[i][2] = wbv1; acc[i][3] = wbv2;
    }
#pragma unroll 4
    for (int k = 0; k < 64; k++) {
      float w0 = sW[k * 64 + lane];
      float w1 = sW[4096 + k * 64 + lane];
      float w2 = sW[8192 + k * 64 + lane];
      float w3 = sW[12288 + k * 64 + lane];
#pragma unroll
      for (int i = 0; i < 8; i++) {
        float a = bcast(hr[i], k);
        acc[i][0] += a * w0; acc[i][1] += a * w1;
        acc[i][2] += a * w2; acc[i][3] += a * w3;
      }
    }
#pragma unroll
    for (int i = 0; i < 8; i++) {
      int n = n0 + i;
      float esv = tanhf(2.f * acc[i][0]);
#pragma unroll
      for (int r = 0; r < 3; r++) {
        int idxrn = r * N_NODES + n;
        float hpv = acc[i][1 + r];
        hp16[(size_t)idxrn * 64 + lane] = (_Float16)hpv;
        float cs = hpv * wa0[r] + esv * wa2[r];
        float cd = hpv * wa1[r];
#pragma unroll
        for (int m = 1; m < 16; m <<= 1) {
          cs += __shfl_xor(cs, m);
          cd += __shfl_xor(cd, m);
        }
        float sv = esv * bb[r];
#pragma unroll
        for (int m = 1; m < 64; m <<= 1) sv += __shfl_xor(sv, m);
        if (k16 == 0) {
          float2 rec2 = make_float2(cs + ab[r], sv);
          *reinterpret_cast<float2*>(&pk[(size_t)idxrn * 8 + hgrp * 2]) = rec2;
          adst[(size_t)idxrn * 4 + hgrp] = cd;
        }
      }
    }
  }
}

// ---------------- fused: per-dst softmax-aggregate + gate + final linear ----------------
// 1024-thread blocks; __launch_bounds__(1024, 2): 2 blocks/CU -> 8 waves/SIMD,
// 64-VGPR cap (R8-R10 verified spill-free at 60 VGPR).
// hp gathered as FP16 (2 lines/edge); pk as float2 {a_head, sdot} (1 line/edge).
#define EDGE_BODY(EE, OA, DS, SD)                                          \
  {                                                                        \
    int s_ = ssrc[EE];                                                     \
    float2 pv_ = *reinterpret_cast<const float2*>(&pkr[s_ * 8 + head2]);   \
    half4v hv_ = *reinterpret_cast<const half4v*>(&hpr16[s_ * 64 + cq]);   \
    float a_ = pv_.x + adh;                                                \
    a_ = a_ >= 0.f ? a_ : 0.01f * a_;                                      \
    float ex_ = __expf(a_);                                                \
    OA.x += ex_ * (float)hv_.x;                                            \
    OA.y += ex_ * (float)hv_.y;                                            \
    OA.z += ex_ * (float)hv_.z;                                            \
    OA.w += ex_ * (float)hv_.w;                                            \
    DS += ex_;                                                             \
    SD += pv_.y;                                                           \
  }

__global__ __launch_bounds__(1024, 2) void k_fused(
    const _Float16* __restrict__ hp16, const float* __restrict__ pk,
    const float* __restrict__ adst, const int* __restrict__ P,
    const int* __restrict__ ssrc, const float* __restrict__ beta,
    const float* __restrict__ lin_w, const float* __restrict__ lin_b,
    float* __restrict__ out) {
  __shared__ __align__(16) float sLW[64 * 196];   // transposed lin_w: [c][j], stride 196
  __shared__ __align__(16) float sHR[16][4][64];  // per-wave hr staging (16 KB)
  int tid = threadIdx.x;
  for (int idx = tid; idx < 192 * 64; idx += 1024) {
    int j = idx >> 6, c = idx & 63;
    sLW[c * 196 + j] = lin_w[idx];
  }
  __syncthreads();
  int lane = tid & 63, wid = tid >> 6;
  int g = blockIdx.x * 16 + wid;  // 4 nodes per wave
  int slot = lane >> 4;           // edge slot 0..3
  int c16 = lane & 15;            // channel-quad index
  int cq = c16 * 4;               // first channel of this lane's quad
  int head = c16 >> 2;            // head of these 4 channels
  int head2 = head * 2;           // float2 offset into pk record
  float y0 = lin_b[lane];
  float y[4] = {y0, y0, y0, y0};
  for (int r = 0; r < 3; r++) {
    const _Float16* __restrict__ hpr16 = hp16 + (size_t)r * N_NODES * 64;
    const float* __restrict__ pkr = pk + (size_t)r * N_NODES * 8;
    float4 b1v = *reinterpret_cast<const float4*>(&beta[r * 128 + 64 + cq]);
#pragma unroll
    for (int i = 0; i < 4; i++) {
      int n = g * 4 + i;
      n = n < N_NODES ? n : N_NODES - 1;  // tail clamp: duplicate work, store-guarded
      int idxrn = r * N_NODES + n;
      int beg = P[idxrn];
      int end = (idxrn + 1 < RN) ? P[idxrn + 1] : RE;
      float adh = adst[idxrn * 4 + head];
      half4v hq_ = *reinterpret_cast<const half4v*>(&hpr16[n * 64 + cq]);
      float4 hpv = make_float4((float)hq_.x, (float)hq_.y, (float)hq_.z,
                               (float)hq_.w);
      float4 oaA = {0.f, 0.f, 0.f, 0.f}, oaB = {0.f, 0.f, 0.f, 0.f};
      float dsA = 0.f, dsB = 0.f, sdA = 0.f, sdB = 0.f;
      int e = beg + slot;
      for (; e + 4 < end; e += 8) {
        EDGE_BODY(e, oaA, dsA, sdA);
        EDGE_BODY(e + 4, oaB, dsB, sdB);
      }
      if (e < end) EDGE_BODY(e, oaA, dsA, sdA);
      float4 oa;
      oa.x = oaA.x + oaB.x;
      oa.y = oaA.y + oaB.y;
      oa.z = oaA.z + oaB.z;
      oa.w = oaA.w + oaB.w;
      float ds = dsA + dsB, sd = sdA + sdB;
      // combine the 4 edge slots (lane bits 4,5)
      oa.x += __shfl_xor(oa.x, 16); oa.x += __shfl_xor(oa.x, 32);
      oa.y += __shfl_xor(oa.y, 16); oa.y += __shfl_xor(oa.y, 32);
      oa.z += __shfl_xor(oa.z, 16); oa.z += __shfl_xor(oa.z, 32);
      oa.w += __shfl_xor(oa.w, 16); oa.w += __shfl_xor(oa.w, 32);
      ds += __shfl_xor(ds, 16); ds += __shfl_xor(ds, 32);
      sd += __shfl_xor(sd, 16); sd += __shfl_xor(sd, 32);
      float inv = 1.f / fmaxf(ds, 1e-20f);
      float4 ov;
      ov.x = oa.x * inv; ov.y = oa.y * inv; ov.z = oa.z * inv; ov.w = oa.w * inv;
      float em = sd / fmaxf((float)(end - beg), 1.f);  // wave-uniform gate es-part
      float gc = ov.x * b1v.x + ov.y * b1v.y + ov.z * b1v.z + ov.w * b1v.w;
      gc += __shfl_xor(gc, 1); gc += __shfl_xor(gc, 2);
      gc += __shfl_xor(gc, 4); gc += __shfl_xor(gc, 8);
      float gt = 1.f / (1.f + __expf(-(gc + em)));
      float4 hrv;
      hrv.x = gt * ov.x + (1.f - gt) * hpv.x;
      hrv.y = gt * ov.y + (1.f - gt) * hpv.y;
      hrv.z = gt * ov.z + (1.f - gt) * hpv.z;
      hrv.w = gt * ov.w + (1.f - gt) * hpv.w;
      if (slot == 0) *reinterpret_cast<float4*>(&sHR[wid][i][cq]) = hrv;
    }
    __builtin_amdgcn_wave_barrier();  // keep LDS write->read order (no cost)
    const float* wrow = &sLW[lane * 196 + r * 64];
    const float* hrow = &sHR[wid][0][0];
#pragma unroll
    for (int j4 = 0; j4 < 64; j4 += 4) {
      float4 wv = *reinterpret_cast<const float4*>(wrow + j4);
#pragma unroll
      for (int i = 0; i < 4; i++) {
        // uniform address across lanes -> LDS broadcast, no conflict, no VALU
        float4 hv = *reinterpret_cast<const float4*>(hrow + i * 64 + j4);
        y[i] += hv.x * wv.x + hv.y * wv.y + hv.z * wv.z + hv.w * wv.w;
      }
    }
    __builtin_amdgcn_wave_barrier();  // reads done before next r overwrites sHR
  }
#pragma unroll
  for (int i = 0; i < 4; i++) {
    int n = g * 4 + i;
    if (n < N_NODES) out[n * 64 + lane] = y[i];
  }
}

extern "C" void kernel_launch(void* const* d_in, const int* in_sizes, int n_in,
                              void* d_out, int out_size, void* d_ws, size_t ws_size,
                              hipStream_t stream) {
  const float* h = (const float*)d_in[0];
  const int* src = (const int*)d_in[1];
  const int* dst = (const int*)d_in[2];
  const float* d_w = (const float*)d_in[3];
  const float* d_b = (const float*)d_in[4];
  const float* w_w = (const float*)d_in[5];
  const float* w_b = (const float*)d_in[6];
  const float* atten_w = (const float*)d_in[7];
  const float* atten_b = (const float*)d_in[8];
  const float* beta = (const float*)d_in[9];
  const float* lin_w = (const float*)d_in[10];
  const float* lin_b = (const float*)d_in[11];
  float* out = (float*)d_out;

  _Float16* hp16 = (_Float16*)d_ws;                    // R*N*64 halves (38.4 MB)
  float* pk = (float*)(hp16 + (size_t)RN * 64);        // R*N*8
  float* adst = pk + (size_t)RN * 8;                   // R*N*4
  int* P = (int*)(adst + (size_t)RN * 4);              // RN
  int* ssrc = P + RN;                                  // RE
  unsigned int* rec = (unsigned int*)(ssrc + RE);      // RE
  int* tot = (int*)(rec + RE);                         // K_BKT
  int* BB = tot + K_BKT;                               // K_BKT+1
  int* cursor = BB + K_BKT + 1;                        // K_BKT

  hipMemsetAsync(tot, 0, K_BKT * sizeof(int), stream);
  k_hist<<<NBLK_A, 256, 0, stream>>>(dst, tot);
  k_scanK<<<1, 256, 0, stream>>>(tot, BB, cursor);
  k_scatterA<<<NBLK_A, 256, 0, stream>>>(src, dst, cursor, rec);
  k_nb<<<K_BKT + NODE_BLKS, 256, 0, stream>>>(rec, BB, P, ssrc, h, d_w, d_b,
                                              w_w, w_b, atten_w, atten_b, beta,
                                              hp16, pk, adst);
  int nfb = (N_NODES + 63) / 64;  // 64 nodes per 1024-thread block
  k_fused<<<nfb, 1024, 0, stream>>>(hp16, pk, adst, P, ssrc, beta, lin_w,
                                    lin_b, out);
}